// Round 1
// baseline (969.641 us; speedup 1.0000x reference)
//
#include <hip/hip_runtime.h>

#define NNODES 100000
#define NEDGES 1600000
#define INC 128
#define HIDC 64
#define HASH_BITS 22
#define HASH_SIZE (1u << HASH_BITS)
#define HASH_MASK (HASH_SIZE - 1)
#define EMPTY_KEY 0xFFFFFFFFFFFFFFFFull

__device__ __forceinline__ unsigned long long mix64(unsigned long long x) {
    x ^= x >> 33; x *= 0xff51afd7ed558ccdull;
    x ^= x >> 33; x *= 0xc4ceb9fe1a85ec53ull;
    x ^= x >> 33;
    return x;
}

// Per edge: full in-degree count (for CSR) + distinct-neighbor count (for norm).
__global__ void count_kernel(const int* __restrict__ src, const int* __restrict__ dst,
                             int* __restrict__ deg, int* __restrict__ dcount,
                             unsigned long long* __restrict__ hash_tab, int n_edges) {
    int e = blockIdx.x * blockDim.x + threadIdx.x;
    if (e >= n_edges) return;
    int s = src[e], d = dst[e];
    atomicAdd(&deg[d], 1);
    if (s == d) return;  // merges with the diagonal of I + A^T; never adds to rowcount
    unsigned long long key = ((unsigned long long)d << 17) | (unsigned)s;
    unsigned slot = (unsigned)mix64(key) & HASH_MASK;
    while (true) {
        unsigned long long prev = atomicCAS(&hash_tab[slot], EMPTY_KEY, key);
        if (prev == EMPTY_KEY) { atomicAdd(&dcount[d], 1); break; }
        if (prev == key) break;
        slot = (slot + 1) & HASH_MASK;
    }
}

// Exclusive scan of deg -> row_off, 1024-element chunks.
__global__ void scan1_kernel(const int* __restrict__ deg, int* __restrict__ row_off,
                             int* __restrict__ partial, int n) {
    __shared__ int sdata[256];
    int t = threadIdx.x;
    int base = blockIdx.x * 1024 + t * 4;
    int v0 = (base + 0 < n) ? deg[base + 0] : 0;
    int v1 = (base + 1 < n) ? deg[base + 1] : 0;
    int v2 = (base + 2 < n) ? deg[base + 2] : 0;
    int v3 = (base + 3 < n) ? deg[base + 3] : 0;
    int sum = v0 + v1 + v2 + v3;
    sdata[t] = sum;
    __syncthreads();
    for (int off = 1; off < 256; off <<= 1) {
        int x = (t >= off) ? sdata[t - off] : 0;
        __syncthreads();
        sdata[t] += x;
        __syncthreads();
    }
    int excl = sdata[t] - sum;
    if (base + 0 < n) row_off[base + 0] = excl;
    if (base + 1 < n) row_off[base + 1] = excl + v0;
    if (base + 2 < n) row_off[base + 2] = excl + v0 + v1;
    if (base + 3 < n) row_off[base + 3] = excl + v0 + v1 + v2;
    if (t == 255) partial[blockIdx.x] = sdata[255];
}

__global__ void scan2_kernel(int* __restrict__ partial, int* __restrict__ row_off,
                             int nchunks, int n) {
    if (threadIdx.x == 0 && blockIdx.x == 0) {
        int run = 0;
        for (int i = 0; i < nchunks; i++) { int t = partial[i]; partial[i] = run; run += t; }
        row_off[n] = run;
    }
}

__global__ void scan3_kernel(int* __restrict__ row_off, int* __restrict__ fill_pos,
                             const int* __restrict__ partial, int n) {
    int i = blockIdx.x * blockDim.x + threadIdx.x;
    if (i >= n) return;
    int v = row_off[i] + partial[i >> 10];
    row_off[i] = v;
    fill_pos[i] = v;
}

__global__ void fill_kernel(const int* __restrict__ src, const int* __restrict__ dst,
                            int* __restrict__ fill_pos, int* __restrict__ csr_src, int n_edges) {
    int e = blockIdx.x * blockDim.x + threadIdx.x;
    if (e >= n_edges) return;
    int d = dst[e];
    int pos = atomicAdd(&fill_pos[d], 1);
    csr_src[pos] = src[e];
}

__global__ void norm_kernel(const int* __restrict__ dcount, float* __restrict__ norm, int n) {
    int i = blockIdx.x * blockDim.x + threadIdx.x;
    if (i < n) norm[i] = 1.0f / (1.0f + (float)dcount[i]);
}

// out[n, c] = b[c] + sum_k x[n, k] * w[k, c];  64 output channels, K in {128, 64}
template <int K>
__global__ void lin_kernel(const float* __restrict__ x, const float* __restrict__ w,
                           const float* __restrict__ b, float* __restrict__ out, int n_nodes) {
    __shared__ float xs[4][K];
    int t = threadIdx.x;
    int node0 = blockIdx.x * 4;
    for (int i = t; i < 4 * K; i += 256) {
        int n = i / K, k = i % K;
        int nn = node0 + n;
        xs[n][k] = (nn < n_nodes) ? x[nn * K + k] : 0.0f;
    }
    __syncthreads();
    int nl = t >> 6, c = t & 63;
    int node = node0 + nl;
    float acc = b[c];
#pragma unroll 8
    for (int k = 0; k < K; k++) acc += xs[nl][k] * w[k * 64 + c];
    if (node < n_nodes) out[node * 64 + c] = acc;
}

// One wave per node: CSR gather-sum + PAN combine (+ optional relu).
__global__ void agg_h_kernel(const float* __restrict__ lin, const int* __restrict__ row_off,
                             const int* __restrict__ csr_src, const float* __restrict__ norm,
                             const float* __restrict__ wpan, float* __restrict__ out,
                             int n_nodes, int do_relu) {
    int t = threadIdx.x;
    int node = blockIdx.x * 4 + (t >> 6);
    int c = t & 63;
    if (node >= n_nodes) return;
    int e0 = row_off[node], e1 = row_off[node + 1];
    float acc = 0.0f;
    for (int e = e0; e < e1; e++) {
        int s = csr_src[e];
        acc += lin[s * 64 + c];
    }
    float w0 = wpan[0];
    float w01 = wpan[0] * wpan[1];
    float v = norm[node] * (w0 * lin[node * 64 + c] + w01 * acc);
    if (do_relu) v = fmaxf(v, 0.0f);
    out[node * 64 + c] = v;
}

// pq[n] = {h[n]@wc[0:64,0], h[n]@wc[0:64,1], h[n]@wc[64:128,0], h[n]@wc[64:128,1]}
__global__ void pq_kernel(const float* __restrict__ h, const float* __restrict__ wc,
                          float* __restrict__ pq, int n_nodes) {
    int t = threadIdx.x;
    int node = blockIdx.x * 4 + (t >> 6);
    int k = t & 63;
    if (node >= n_nodes) return;
    float hv = h[node * 64 + k];
    float p0 = hv * wc[k * 2 + 0];
    float p1 = hv * wc[k * 2 + 1];
    float q0 = hv * wc[128 + k * 2 + 0];
    float q1 = hv * wc[128 + k * 2 + 1];
    for (int off = 32; off; off >>= 1) {
        p0 += __shfl_xor(p0, off);
        p1 += __shfl_xor(p1, off);
        q0 += __shfl_xor(q0, off);
        q1 += __shfl_xor(q1, off);
    }
    if (k == 0) {
        float4 v = make_float4(p0, p1, q0, q1);
        *(float4*)(pq + node * 4) = v;
    }
}

__global__ void edge_out_kernel(const int* __restrict__ src, const int* __restrict__ dst,
                                const float* __restrict__ pq, const float* __restrict__ bc,
                                float* __restrict__ out, int n_edges) {
    int e = blockIdx.x * blockDim.x + threadIdx.x;
    if (e >= n_edges) return;
    int r = src[e], c = dst[e];
    float2 p = *(const float2*)(pq + r * 4);
    float2 q = *(const float2*)(pq + c * 4 + 2);
    float2 o = make_float2(p.x + q.x + bc[0], p.y + q.y + bc[1]);
    *(float2*)(out + e * 2) = o;
}

extern "C" void kernel_launch(void* const* d_in, const int* in_sizes, int n_in,
                              void* d_out, int out_size, void* d_ws, size_t ws_size,
                              hipStream_t stream) {
    const float* x      = (const float*)d_in[0];
    const int*   eidx   = (const int*)d_in[1];
    const float* w1_lin = (const float*)d_in[2];
    const float* b1_lin = (const float*)d_in[3];
    const float* w1_pan = (const float*)d_in[4];
    const float* w2_lin = (const float*)d_in[5];
    const float* b2_lin = (const float*)d_in[6];
    const float* w2_pan = (const float*)d_in[7];
    const float* wc     = (const float*)d_in[8];
    const float* bc     = (const float*)d_in[9];
    float* out = (float*)d_out;

    const int* src = eidx;           // edge_index[0]
    const int* dst = eidx + NEDGES;  // edge_index[1]

    // ---- workspace carve-up (all 256B-aligned) ----
    char* ws = (char*)d_ws;
    size_t off = 0;
    auto carve = [&](size_t bytes) {
        char* p = ws + off;
        off = (off + bytes + 255) & ~(size_t)255;
        return p;
    };
    unsigned long long* hash_tab = (unsigned long long*)carve((size_t)HASH_SIZE * 8);  // 32 MB
    int*   deg      = (int*)carve((size_t)NNODES * 4);
    int*   dcount   = (int*)carve((size_t)NNODES * 4);
    int*   row_off  = (int*)carve((size_t)(NNODES + 1) * 4);
    int*   fill_pos = (int*)carve((size_t)NNODES * 4);
    int*   partial  = (int*)carve((size_t)128 * 4);
    int*   csr_src  = (int*)carve((size_t)NEDGES * 4);
    float* nrm      = (float*)carve((size_t)NNODES * 4);
    float* bufA     = (float*)carve((size_t)NNODES * HIDC * 4);  // 25.6 MB
    float* bufB     = (float*)carve((size_t)NNODES * HIDC * 4);  // 25.6 MB
    float* pq       = (float*)carve((size_t)NNODES * 4 * 4);
    (void)ws_size; (void)in_sizes; (void)n_in; (void)out_size;

    const int nchunks = (NNODES + 1023) / 1024;  // 98

    // init (ws is re-poisoned to 0xAA before every timed launch)
    hipMemsetAsync(hash_tab, 0xFF, (size_t)HASH_SIZE * 8, stream);
    hipMemsetAsync(deg, 0, (size_t)NNODES * 4, stream);
    hipMemsetAsync(dcount, 0, (size_t)NNODES * 4, stream);

    // degree + distinct-neighbor counts
    count_kernel<<<NEDGES / 256, 256, 0, stream>>>(src, dst, deg, dcount, hash_tab, NEDGES);

    // CSR row offsets (exclusive scan)
    scan1_kernel<<<nchunks, 256, 0, stream>>>(deg, row_off, partial, NNODES);
    scan2_kernel<<<1, 1, 0, stream>>>(partial, row_off, nchunks, NNODES);
    scan3_kernel<<<(NNODES + 255) / 256, 256, 0, stream>>>(row_off, fill_pos, partial, NNODES);

    // CSR adjacency fill
    fill_kernel<<<NEDGES / 256, 256, 0, stream>>>(src, dst, fill_pos, csr_src, NEDGES);

    // norm = 1 / rowcount(I + A^T)
    norm_kernel<<<(NNODES + 255) / 256, 256, 0, stream>>>(dcount, nrm, NNODES);

    // layer 1: lin -> aggregate -> combine + relu
    lin_kernel<INC><<<NNODES / 4, 256, 0, stream>>>(x, w1_lin, b1_lin, bufA, NNODES);
    agg_h_kernel<<<NNODES / 4, 256, 0, stream>>>(bufA, row_off, csr_src, nrm, w1_pan, bufB,
                                                 NNODES, 1);

    // layer 2
    lin_kernel<HIDC><<<NNODES / 4, 256, 0, stream>>>(bufB, w2_lin, b2_lin, bufA, NNODES);
    agg_h_kernel<<<NNODES / 4, 256, 0, stream>>>(bufA, row_off, csr_src, nrm, w2_pan, bufB,
                                                 NNODES, 0);

    // edge head: out[e] = p[src[e]] + q[dst[e]] + bc
    pq_kernel<<<NNODES / 4, 256, 0, stream>>>(bufB, wc, pq, NNODES);
    edge_out_kernel<<<NEDGES / 256, 256, 0, stream>>>(src, dst, pq, bc, out, NEDGES);
}

// Round 2
// 850.204 us; speedup vs baseline: 1.1405x; 1.1405x over previous
//
#include <hip/hip_runtime.h>

#define NNODES 100000
#define NEDGES 1600000
#define INC 128
#define HIDC 64

// Per edge: in-degree count (for CSR).
__global__ void count_kernel(const int* __restrict__ dst, int* __restrict__ deg, int n_edges) {
    int e = blockIdx.x * blockDim.x + threadIdx.x;
    if (e >= n_edges) return;
    atomicAdd(&deg[dst[e]], 1);
}

// Exclusive scan of deg -> row_off, 1024-element chunks.
__global__ void scan1_kernel(const int* __restrict__ deg, int* __restrict__ row_off,
                             int* __restrict__ partial, int n) {
    __shared__ int sdata[256];
    int t = threadIdx.x;
    int base = blockIdx.x * 1024 + t * 4;
    int v0 = (base + 0 < n) ? deg[base + 0] : 0;
    int v1 = (base + 1 < n) ? deg[base + 1] : 0;
    int v2 = (base + 2 < n) ? deg[base + 2] : 0;
    int v3 = (base + 3 < n) ? deg[base + 3] : 0;
    int sum = v0 + v1 + v2 + v3;
    sdata[t] = sum;
    __syncthreads();
    for (int off = 1; off < 256; off <<= 1) {
        int x = (t >= off) ? sdata[t - off] : 0;
        __syncthreads();
        sdata[t] += x;
        __syncthreads();
    }
    int excl = sdata[t] - sum;
    if (base + 0 < n) row_off[base + 0] = excl;
    if (base + 1 < n) row_off[base + 1] = excl + v0;
    if (base + 2 < n) row_off[base + 2] = excl + v0 + v1;
    if (base + 3 < n) row_off[base + 3] = excl + v0 + v1 + v2;
    if (t == 255) partial[blockIdx.x] = sdata[255];
}

// Scan the 98 chunk totals in parallel (one 128-thread block).
__global__ void scan2_kernel(int* __restrict__ partial, int* __restrict__ row_off,
                             int nchunks, int n) {
    __shared__ int sdata[128];
    int t = threadIdx.x;
    int v = (t < nchunks) ? partial[t] : 0;
    sdata[t] = v;
    __syncthreads();
    for (int off = 1; off < 128; off <<= 1) {
        int x = (t >= off) ? sdata[t - off] : 0;
        __syncthreads();
        sdata[t] += x;
        __syncthreads();
    }
    if (t < nchunks) partial[t] = sdata[t] - v;  // exclusive chunk offset
    if (t == 127) row_off[n] = sdata[127];       // grand total
}

__global__ void scan3_kernel(int* __restrict__ row_off, int* __restrict__ fill_pos,
                             const int* __restrict__ partial, int n) {
    int i = blockIdx.x * blockDim.x + threadIdx.x;
    if (i >= n) return;
    int v = row_off[i] + partial[i >> 10];
    row_off[i] = v;
    fill_pos[i] = v;
}

__global__ void fill_kernel(const int* __restrict__ src, const int* __restrict__ dst,
                            int* __restrict__ fill_pos, int* __restrict__ csr_src, int n_edges) {
    int e = blockIdx.x * blockDim.x + threadIdx.x;
    if (e >= n_edges) return;
    int d = dst[e];
    int pos = atomicAdd(&fill_pos[d], 1);
    csr_src[pos] = src[e];
}

// One wave per node: count distinct incoming sources (!= self) in the CSR row.
// norm = 1 / (1 + distinct)   [the +1 is the I-diagonal of M = I + A^T]
__global__ void norm_dedup_kernel(const int* __restrict__ row_off,
                                  const int* __restrict__ csr_src,
                                  float* __restrict__ norm, int n_nodes) {
    int t = threadIdx.x;
    int node = blockIdx.x * 4 + (t >> 6);
    int lane = t & 63;
    if (node >= n_nodes) return;
    int e0 = row_off[node], e1 = row_off[node + 1];
    int count = 0;
    for (int base = e0; base < e1; base += 64) {
        int idx = base + lane;
        int v = (idx < e1) ? csr_src[idx] : -1;
        // intra-chunk: is some earlier lane holding the same value?
        bool dup = false;
        for (int j = 0; j < 64; j++) {
            int vj = __shfl(v, j);
            if (j < lane && vj == v) dup = true;
        }
        bool cand = (idx < e1) && (v != node) && !dup;
        // previous chunks (degree > 64 only; rare): serial scan, L1/L2-hit
        if (cand && base > e0) {
            for (int j = e0; j < base; j++) {
                if (csr_src[j] == v) { cand = false; break; }
            }
        }
        count += cand ? 1 : 0;
    }
    for (int off = 32; off; off >>= 1) count += __shfl_xor(count, off);
    if (lane == 0) norm[node] = 1.0f / (1.0f + (float)count);
}

// out[n, c] = b[c] + sum_k x[n, k] * w[k, c];  64 output channels, K in {128, 64}
template <int K>
__global__ void lin_kernel(const float* __restrict__ x, const float* __restrict__ w,
                           const float* __restrict__ b, float* __restrict__ out, int n_nodes) {
    __shared__ float xs[4][K];
    int t = threadIdx.x;
    int node0 = blockIdx.x * 4;
    for (int i = t; i < 4 * K; i += 256) {
        int n = i / K, k = i % K;
        int nn = node0 + n;
        xs[n][k] = (nn < n_nodes) ? x[nn * K + k] : 0.0f;
    }
    __syncthreads();
    int nl = t >> 6, c = t & 63;
    int node = node0 + nl;
    float acc = b[c];
#pragma unroll 8
    for (int k = 0; k < K; k++) acc += xs[nl][k] * w[k * 64 + c];
    if (node < n_nodes) out[node * 64 + c] = acc;
}

// One wave per node: CSR gather-sum + PAN combine (+ optional relu).
__global__ void agg_h_kernel(const float* __restrict__ lin, const int* __restrict__ row_off,
                             const int* __restrict__ csr_src, const float* __restrict__ norm,
                             const float* __restrict__ wpan, float* __restrict__ out,
                             int n_nodes, int do_relu) {
    int t = threadIdx.x;
    int node = blockIdx.x * 4 + (t >> 6);
    int c = t & 63;
    if (node >= n_nodes) return;
    int e0 = row_off[node], e1 = row_off[node + 1];
    float acc = 0.0f;
    for (int e = e0; e < e1; e++) {
        int s = csr_src[e];
        acc += lin[s * 64 + c];
    }
    float w0 = wpan[0];
    float w01 = wpan[0] * wpan[1];
    float v = norm[node] * (w0 * lin[node * 64 + c] + w01 * acc);
    if (do_relu) v = fmaxf(v, 0.0f);
    out[node * 64 + c] = v;
}

// pq[n] = {h[n]@wc[0:64,0], h[n]@wc[0:64,1], h[n]@wc[64:128,0], h[n]@wc[64:128,1]}
__global__ void pq_kernel(const float* __restrict__ h, const float* __restrict__ wc,
                          float* __restrict__ pq, int n_nodes) {
    int t = threadIdx.x;
    int node = blockIdx.x * 4 + (t >> 6);
    int k = t & 63;
    if (node >= n_nodes) return;
    float hv = h[node * 64 + k];
    float p0 = hv * wc[k * 2 + 0];
    float p1 = hv * wc[k * 2 + 1];
    float q0 = hv * wc[128 + k * 2 + 0];
    float q1 = hv * wc[128 + k * 2 + 1];
    for (int off = 32; off; off >>= 1) {
        p0 += __shfl_xor(p0, off);
        p1 += __shfl_xor(p1, off);
        q0 += __shfl_xor(q0, off);
        q1 += __shfl_xor(q1, off);
    }
    if (k == 0) {
        float4 v = make_float4(p0, p1, q0, q1);
        *(float4*)(pq + node * 4) = v;
    }
}

__global__ void edge_out_kernel(const int* __restrict__ src, const int* __restrict__ dst,
                                const float* __restrict__ pq, const float* __restrict__ bc,
                                float* __restrict__ out, int n_edges) {
    int e = blockIdx.x * blockDim.x + threadIdx.x;
    if (e >= n_edges) return;
    int r = src[e], c = dst[e];
    float2 p = *(const float2*)(pq + r * 4);
    float2 q = *(const float2*)(pq + c * 4 + 2);
    float2 o = make_float2(p.x + q.x + bc[0], p.y + q.y + bc[1]);
    *(float2*)(out + e * 2) = o;
}

extern "C" void kernel_launch(void* const* d_in, const int* in_sizes, int n_in,
                              void* d_out, int out_size, void* d_ws, size_t ws_size,
                              hipStream_t stream) {
    const float* x      = (const float*)d_in[0];
    const int*   eidx   = (const int*)d_in[1];
    const float* w1_lin = (const float*)d_in[2];
    const float* b1_lin = (const float*)d_in[3];
    const float* w1_pan = (const float*)d_in[4];
    const float* w2_lin = (const float*)d_in[5];
    const float* b2_lin = (const float*)d_in[6];
    const float* w2_pan = (const float*)d_in[7];
    const float* wc     = (const float*)d_in[8];
    const float* bc     = (const float*)d_in[9];
    float* out = (float*)d_out;

    const int* src = eidx;           // edge_index[0]
    const int* dst = eidx + NEDGES;  // edge_index[1]

    // ---- workspace carve-up (all 256B-aligned) ----
    char* ws = (char*)d_ws;
    size_t off = 0;
    auto carve = [&](size_t bytes) {
        char* p = ws + off;
        off = (off + bytes + 255) & ~(size_t)255;
        return p;
    };
    int*   deg      = (int*)carve((size_t)NNODES * 4);
    int*   row_off  = (int*)carve((size_t)(NNODES + 1) * 4);
    int*   fill_pos = (int*)carve((size_t)NNODES * 4);
    int*   partial  = (int*)carve((size_t)128 * 4);
    int*   csr_src  = (int*)carve((size_t)NEDGES * 4);
    float* nrm      = (float*)carve((size_t)NNODES * 4);
    float* bufA     = (float*)carve((size_t)NNODES * HIDC * 4);  // 25.6 MB
    float* bufB     = (float*)carve((size_t)NNODES * HIDC * 4);  // 25.6 MB
    float* pq       = (float*)carve((size_t)NNODES * 4 * 4);
    (void)ws_size; (void)in_sizes; (void)n_in; (void)out_size;

    const int nchunks = (NNODES + 1023) / 1024;  // 98

    hipMemsetAsync(deg, 0, (size_t)NNODES * 4, stream);

    // in-degree counts
    count_kernel<<<NEDGES / 256, 256, 0, stream>>>(dst, deg, NEDGES);

    // CSR row offsets (exclusive scan)
    scan1_kernel<<<nchunks, 256, 0, stream>>>(deg, row_off, partial, NNODES);
    scan2_kernel<<<1, 128, 0, stream>>>(partial, row_off, nchunks, NNODES);
    scan3_kernel<<<(NNODES + 255) / 256, 256, 0, stream>>>(row_off, fill_pos, partial, NNODES);

    // CSR adjacency fill
    fill_kernel<<<NEDGES / 256, 256, 0, stream>>>(src, dst, fill_pos, csr_src, NEDGES);

    // norm = 1 / rowcount(I + A^T) via per-row dedup
    norm_dedup_kernel<<<(NNODES + 3) / 4, 256, 0, stream>>>(row_off, csr_src, nrm, NNODES);

    // layer 1: lin -> aggregate -> combine + relu
    lin_kernel<INC><<<NNODES / 4, 256, 0, stream>>>(x, w1_lin, b1_lin, bufA, NNODES);
    agg_h_kernel<<<NNODES / 4, 256, 0, stream>>>(bufA, row_off, csr_src, nrm, w1_pan, bufB,
                                                 NNODES, 1);

    // layer 2
    lin_kernel<HIDC><<<NNODES / 4, 256, 0, stream>>>(bufB, w2_lin, b2_lin, bufA, NNODES);
    agg_h_kernel<<<NNODES / 4, 256, 0, stream>>>(bufA, row_off, csr_src, nrm, w2_pan, bufB,
                                                 NNODES, 0);

    // edge head: out[e] = p[src[e]] + q[dst[e]] + bc
    pq_kernel<<<NNODES / 4, 256, 0, stream>>>(bufB, wc, pq, NNODES);
    edge_out_kernel<<<NEDGES / 256, 256, 0, stream>>>(src, dst, pq, bc, out, NEDGES);
}

// Round 3
// 653.829 us; speedup vs baseline: 1.4830x; 1.3003x over previous
//
#include <hip/hip_runtime.h>

#define NNODES 100000
#define NEDGES 1600000
#define INC 128
#define HIDC 64

// Per edge: in-degree count (for CSR).
__global__ void count_kernel(const int* __restrict__ dst, int* __restrict__ deg, int n_edges) {
    int e = blockIdx.x * blockDim.x + threadIdx.x;
    if (e >= n_edges) return;
    atomicAdd(&deg[dst[e]], 1);
}

// Exclusive scan of deg -> row_off, 1024-element chunks.
__global__ void scan1_kernel(const int* __restrict__ deg, int* __restrict__ row_off,
                             int* __restrict__ partial, int n) {
    __shared__ int sdata[256];
    int t = threadIdx.x;
    int base = blockIdx.x * 1024 + t * 4;
    int v0 = (base + 0 < n) ? deg[base + 0] : 0;
    int v1 = (base + 1 < n) ? deg[base + 1] : 0;
    int v2 = (base + 2 < n) ? deg[base + 2] : 0;
    int v3 = (base + 3 < n) ? deg[base + 3] : 0;
    int sum = v0 + v1 + v2 + v3;
    sdata[t] = sum;
    __syncthreads();
    for (int off = 1; off < 256; off <<= 1) {
        int x = (t >= off) ? sdata[t - off] : 0;
        __syncthreads();
        sdata[t] += x;
        __syncthreads();
    }
    int excl = sdata[t] - sum;
    if (base + 0 < n) row_off[base + 0] = excl;
    if (base + 1 < n) row_off[base + 1] = excl + v0;
    if (base + 2 < n) row_off[base + 2] = excl + v0 + v1;
    if (base + 3 < n) row_off[base + 3] = excl + v0 + v1 + v2;
    if (t == 255) partial[blockIdx.x] = sdata[255];
}

// Scan the 98 chunk totals in parallel (one 128-thread block).
__global__ void scan2_kernel(int* __restrict__ partial, int* __restrict__ row_off,
                             int nchunks, int n) {
    __shared__ int sdata[128];
    int t = threadIdx.x;
    int v = (t < nchunks) ? partial[t] : 0;
    sdata[t] = v;
    __syncthreads();
    for (int off = 1; off < 128; off <<= 1) {
        int x = (t >= off) ? sdata[t - off] : 0;
        __syncthreads();
        sdata[t] += x;
        __syncthreads();
    }
    if (t < nchunks) partial[t] = sdata[t] - v;  // exclusive chunk offset
    if (t == 127) row_off[n] = sdata[127];       // grand total
}

__global__ void scan3_kernel(int* __restrict__ row_off, int* __restrict__ fill_pos,
                             const int* __restrict__ partial, int n) {
    int i = blockIdx.x * blockDim.x + threadIdx.x;
    if (i >= n) return;
    int v = row_off[i] + partial[i >> 10];
    row_off[i] = v;
    fill_pos[i] = v;
}

__global__ void fill_kernel(const int* __restrict__ src, const int* __restrict__ dst,
                            int* __restrict__ fill_pos, int* __restrict__ csr_src, int n_edges) {
    int e = blockIdx.x * blockDim.x + threadIdx.x;
    if (e >= n_edges) return;
    int d = dst[e];
    int pos = atomicAdd(&fill_pos[d], 1);
    csr_src[pos] = src[e];
}

// One wave per node: count distinct incoming sources (!= self) in the CSR row.
// norm = 1 / (1 + distinct)   [the +1 is the I-diagonal of M = I + A^T]
__global__ void norm_dedup_kernel(const int* __restrict__ row_off,
                                  const int* __restrict__ csr_src,
                                  float* __restrict__ norm, int n_nodes) {
    int t = threadIdx.x;
    int node = blockIdx.x * 4 + (t >> 6);
    int lane = t & 63;
    if (node >= n_nodes) return;
    int e0 = row_off[node], e1 = row_off[node + 1];
    int count = 0;
    for (int base = e0; base < e1; base += 64) {
        int idx = base + lane;
        int v = (idx < e1) ? csr_src[idx] : -1;
        // intra-chunk: is some earlier lane holding the same value?
        bool dup = false;
        for (int j = 0; j < 64; j++) {
            int vj = __shfl(v, j);
            if (j < lane && vj == v) dup = true;
        }
        bool cand = (idx < e1) && (v != node) && !dup;
        // previous chunks (degree > 64 only; rare): serial scan, L1/L2-hit
        if (cand && base > e0) {
            for (int j = e0; j < base; j++) {
                if (csr_src[j] == v) { cand = false; break; }
            }
        }
        count += cand ? 1 : 0;
    }
    for (int off = 32; off; off >>= 1) count += __shfl_xor(count, off);
    if (lane == 0) norm[node] = 1.0f / (1.0f + (float)count);
}

// out[n, c] = b[c] + sum_k x[n, k] * w[k, c];  64 output channels, K in {128, 64}
template <int K>
__global__ void lin_kernel(const float* __restrict__ x, const float* __restrict__ w,
                           const float* __restrict__ b, float* __restrict__ out, int n_nodes) {
    __shared__ float xs[4][K];
    int t = threadIdx.x;
    int node0 = blockIdx.x * 4;
    for (int i = t; i < 4 * K; i += 256) {
        int n = i / K, k = i % K;
        int nn = node0 + n;
        xs[n][k] = (nn < n_nodes) ? x[nn * K + k] : 0.0f;
    }
    __syncthreads();
    int nl = t >> 6, c = t & 63;
    int node = node0 + nl;
    float acc = b[c];
#pragma unroll 8
    for (int k = 0; k < K; k++) acc += xs[nl][k] * w[k * 64 + c];
    if (node < n_nodes) out[node * 64 + c] = acc;
}

// 8-wide-unrolled CSR gather-sum for one node (lane = channel).
__device__ __forceinline__ float gather_row_sum(const float* __restrict__ lin,
                                                const int* __restrict__ csr_src,
                                                int e0, int e1, int c) {
    float acc = 0.0f;
    int e = e0;
    for (; e + 8 <= e1; e += 8) {
        int s0 = csr_src[e + 0], s1 = csr_src[e + 1];
        int s2 = csr_src[e + 2], s3 = csr_src[e + 3];
        int s4 = csr_src[e + 4], s5 = csr_src[e + 5];
        int s6 = csr_src[e + 6], s7 = csr_src[e + 7];
        float v0 = lin[s0 * 64 + c], v1 = lin[s1 * 64 + c];
        float v2 = lin[s2 * 64 + c], v3 = lin[s3 * 64 + c];
        float v4 = lin[s4 * 64 + c], v5 = lin[s5 * 64 + c];
        float v6 = lin[s6 * 64 + c], v7 = lin[s7 * 64 + c];
        acc += ((v0 + v1) + (v2 + v3)) + ((v4 + v5) + (v6 + v7));
    }
    if (e + 4 <= e1) {
        int s0 = csr_src[e + 0], s1 = csr_src[e + 1];
        int s2 = csr_src[e + 2], s3 = csr_src[e + 3];
        float v0 = lin[s0 * 64 + c], v1 = lin[s1 * 64 + c];
        float v2 = lin[s2 * 64 + c], v3 = lin[s3 * 64 + c];
        acc += (v0 + v1) + (v2 + v3);
        e += 4;
    }
    for (; e < e1; e++) acc += lin[csr_src[e] * 64 + c];
    return acc;
}

// One wave per node: CSR gather-sum + PAN combine + relu (layer 1).
__global__ void agg_h_kernel(const float* __restrict__ lin, const int* __restrict__ row_off,
                             const int* __restrict__ csr_src, const float* __restrict__ norm,
                             const float* __restrict__ wpan, float* __restrict__ out,
                             int n_nodes) {
    int t = threadIdx.x;
    int node = blockIdx.x * 4 + (t >> 6);
    int c = t & 63;
    if (node >= n_nodes) return;
    int e0 = row_off[node], e1 = row_off[node + 1];
    float acc = gather_row_sum(lin, csr_src, e0, e1, c);
    float w0 = wpan[0];
    float w01 = wpan[0] * wpan[1];
    float v = norm[node] * (w0 * lin[node * 64 + c] + w01 * acc);
    out[node * 64 + c] = fmaxf(v, 0.0f);
}

// Layer 2 aggregate fused with the edge-head projection:
// pq[n] = {h2[n]@wc[0:64,0], h2[n]@wc[0:64,1], h2[n]@wc[64:128,0], h2[n]@wc[64:128,1]}
__global__ void agg_pq_kernel(const float* __restrict__ lin, const int* __restrict__ row_off,
                              const int* __restrict__ csr_src, const float* __restrict__ norm,
                              const float* __restrict__ wpan, const float* __restrict__ wc,
                              float* __restrict__ pq, int n_nodes) {
    int t = threadIdx.x;
    int node = blockIdx.x * 4 + (t >> 6);
    int c = t & 63;
    if (node >= n_nodes) return;
    int e0 = row_off[node], e1 = row_off[node + 1];
    float acc = gather_row_sum(lin, csr_src, e0, e1, c);
    float w0 = wpan[0];
    float w01 = wpan[0] * wpan[1];
    float v = norm[node] * (w0 * lin[node * 64 + c] + w01 * acc);  // h2[node, c]
    float p0 = v * wc[c * 2 + 0];
    float p1 = v * wc[c * 2 + 1];
    float q0 = v * wc[128 + c * 2 + 0];
    float q1 = v * wc[128 + c * 2 + 1];
    for (int off = 32; off; off >>= 1) {
        p0 += __shfl_xor(p0, off);
        p1 += __shfl_xor(p1, off);
        q0 += __shfl_xor(q0, off);
        q1 += __shfl_xor(q1, off);
    }
    if (c == 0) {
        float4 o = make_float4(p0, p1, q0, q1);
        *(float4*)(pq + node * 4) = o;
    }
}

__global__ void edge_out_kernel(const int* __restrict__ src, const int* __restrict__ dst,
                                const float* __restrict__ pq, const float* __restrict__ bc,
                                float* __restrict__ out, int n_edges) {
    int e = blockIdx.x * blockDim.x + threadIdx.x;
    if (e >= n_edges) return;
    int r = src[e], c = dst[e];
    float2 p = *(const float2*)(pq + r * 4);
    float2 q = *(const float2*)(pq + c * 4 + 2);
    float2 o = make_float2(p.x + q.x + bc[0], p.y + q.y + bc[1]);
    *(float2*)(out + e * 2) = o;
}

extern "C" void kernel_launch(void* const* d_in, const int* in_sizes, int n_in,
                              void* d_out, int out_size, void* d_ws, size_t ws_size,
                              hipStream_t stream) {
    const float* x      = (const float*)d_in[0];
    const int*   eidx   = (const int*)d_in[1];
    const float* w1_lin = (const float*)d_in[2];
    const float* b1_lin = (const float*)d_in[3];
    const float* w1_pan = (const float*)d_in[4];
    const float* w2_lin = (const float*)d_in[5];
    const float* b2_lin = (const float*)d_in[6];
    const float* w2_pan = (const float*)d_in[7];
    const float* wc     = (const float*)d_in[8];
    const float* bc     = (const float*)d_in[9];
    float* out = (float*)d_out;

    const int* src = eidx;           // edge_index[0]
    const int* dst = eidx + NEDGES;  // edge_index[1]

    // ---- workspace carve-up (all 256B-aligned) ----
    char* ws = (char*)d_ws;
    size_t off = 0;
    auto carve = [&](size_t bytes) {
        char* p = ws + off;
        off = (off + bytes + 255) & ~(size_t)255;
        return p;
    };
    int*   deg      = (int*)carve((size_t)NNODES * 4);
    int*   row_off  = (int*)carve((size_t)(NNODES + 1) * 4);
    int*   fill_pos = (int*)carve((size_t)NNODES * 4);
    int*   partial  = (int*)carve((size_t)128 * 4);
    int*   csr_src  = (int*)carve((size_t)NEDGES * 4);
    float* nrm      = (float*)carve((size_t)NNODES * 4);
    float* bufA     = (float*)carve((size_t)NNODES * HIDC * 4);  // 25.6 MB
    float* bufB     = (float*)carve((size_t)NNODES * HIDC * 4);  // 25.6 MB
    float* pq       = (float*)carve((size_t)NNODES * 4 * 4);
    (void)ws_size; (void)in_sizes; (void)n_in; (void)out_size;

    const int nchunks = (NNODES + 1023) / 1024;  // 98

    hipMemsetAsync(deg, 0, (size_t)NNODES * 4, stream);

    // in-degree counts
    count_kernel<<<NEDGES / 256, 256, 0, stream>>>(dst, deg, NEDGES);

    // CSR row offsets (exclusive scan)
    scan1_kernel<<<nchunks, 256, 0, stream>>>(deg, row_off, partial, NNODES);
    scan2_kernel<<<1, 128, 0, stream>>>(partial, row_off, nchunks, NNODES);
    scan3_kernel<<<(NNODES + 255) / 256, 256, 0, stream>>>(row_off, fill_pos, partial, NNODES);

    // CSR adjacency fill
    fill_kernel<<<NEDGES / 256, 256, 0, stream>>>(src, dst, fill_pos, csr_src, NEDGES);

    // norm = 1 / rowcount(I + A^T) via per-row dedup
    norm_dedup_kernel<<<(NNODES + 3) / 4, 256, 0, stream>>>(row_off, csr_src, nrm, NNODES);

    // layer 1: lin -> aggregate -> combine + relu
    lin_kernel<INC><<<NNODES / 4, 256, 0, stream>>>(x, w1_lin, b1_lin, bufA, NNODES);
    agg_h_kernel<<<NNODES / 4, 256, 0, stream>>>(bufA, row_off, csr_src, nrm, w1_pan, bufB,
                                                 NNODES);

    // layer 2: lin -> aggregate fused with edge-head projection
    lin_kernel<HIDC><<<NNODES / 4, 256, 0, stream>>>(bufB, w2_lin, b2_lin, bufA, NNODES);
    agg_pq_kernel<<<NNODES / 4, 256, 0, stream>>>(bufA, row_off, csr_src, nrm, w2_pan, wc,
                                                  pq, NNODES);

    // edge head: out[e] = p[src[e]] + q[dst[e]] + bc
    edge_out_kernel<<<NEDGES / 256, 256, 0, stream>>>(src, dst, pq, bc, out, NEDGES);
}

// Round 4
// 577.346 us; speedup vs baseline: 1.6795x; 1.1325x over previous
//
#include <hip/hip_runtime.h>

#define NNODES 100000
#define NEDGES 1600000
#define INC 128
#define HIDC 64
#define BSHIFT 9                      // 512 nodes per bucket
#define NB ((NNODES + 511) / 512)     // 196 buckets
#define TILE 8192                     // edges per fill1 workgroup (32/thread)

// Per edge: in-degree count (for CSR).
__global__ void count_kernel(const int* __restrict__ dst, int* __restrict__ deg, int n_edges) {
    int e = blockIdx.x * blockDim.x + threadIdx.x;
    if (e >= n_edges) return;
    atomicAdd(&deg[dst[e]], 1);
}

// Exclusive scan of deg -> row_off, 1024-element chunks.
__global__ void scan1_kernel(const int* __restrict__ deg, int* __restrict__ row_off,
                             int* __restrict__ partial, int n) {
    __shared__ int sdata[256];
    int t = threadIdx.x;
    int base = blockIdx.x * 1024 + t * 4;
    int v0 = (base + 0 < n) ? deg[base + 0] : 0;
    int v1 = (base + 1 < n) ? deg[base + 1] : 0;
    int v2 = (base + 2 < n) ? deg[base + 2] : 0;
    int v3 = (base + 3 < n) ? deg[base + 3] : 0;
    int sum = v0 + v1 + v2 + v3;
    sdata[t] = sum;
    __syncthreads();
    for (int off = 1; off < 256; off <<= 1) {
        int x = (t >= off) ? sdata[t - off] : 0;
        __syncthreads();
        sdata[t] += x;
        __syncthreads();
    }
    int excl = sdata[t] - sum;
    if (base + 0 < n) row_off[base + 0] = excl;
    if (base + 1 < n) row_off[base + 1] = excl + v0;
    if (base + 2 < n) row_off[base + 2] = excl + v0 + v1;
    if (base + 3 < n) row_off[base + 3] = excl + v0 + v1 + v2;
    if (t == 255) partial[blockIdx.x] = sdata[255];
}

// Scan the 98 chunk totals in parallel (one 128-thread block).
__global__ void scan2_kernel(int* __restrict__ partial, int* __restrict__ row_off,
                             int nchunks, int n) {
    __shared__ int sdata[128];
    int t = threadIdx.x;
    int v = (t < nchunks) ? partial[t] : 0;
    sdata[t] = v;
    __syncthreads();
    for (int off = 1; off < 128; off <<= 1) {
        int x = (t >= off) ? sdata[t - off] : 0;
        __syncthreads();
        sdata[t] += x;
        __syncthreads();
    }
    if (t < nchunks) partial[t] = sdata[t] - v;  // exclusive chunk offset
    if (t == 127) row_off[n] = sdata[127];       // grand total
}

__global__ void scan3_kernel(int* __restrict__ row_off, const int* __restrict__ partial, int n) {
    int i = blockIdx.x * blockDim.x + threadIdx.x;
    if (i >= n) return;
    row_off[i] += partial[i >> 10];
}

// fill pass 1: bin edges into bucket-contiguous staging chunks.
// staged word = (dst & 511) << 17 | src   (src < 2^17, dlocal < 2^9)
__global__ void fill1_kernel(const int* __restrict__ src, const int* __restrict__ dst,
                             const int* __restrict__ row_off, int* __restrict__ bucket_fill,
                             unsigned int* __restrict__ staging, int n_edges) {
    __shared__ int cnt[NB];
    __shared__ int basepos[NB];
    int t = threadIdx.x;
    for (int i = t; i < NB; i += 256) cnt[i] = 0;
    __syncthreads();
    int tile0 = blockIdx.x * TILE;
    unsigned int sv[32];
    int meta[32];
#pragma unroll
    for (int i = 0; i < 32; i++) {
        int e = tile0 + i * 256 + t;
        meta[i] = -1;
        sv[i] = 0;
        if (e < n_edges) {
            int s = src[e], d = dst[e];
            int b = d >> BSHIFT;
            int r = atomicAdd(&cnt[b], 1);      // rank within (tile, bucket); < TILE
            meta[i] = (b << 13) | r;
            sv[i] = ((unsigned)(d & 511) << 17) | (unsigned)s;
        }
    }
    __syncthreads();
    for (int i = t; i < NB; i += 256) {
        int c = cnt[i];
        int g = (c > 0) ? atomicAdd(&bucket_fill[i], c) : 0;
        basepos[i] = row_off[i << BSHIFT] + g;  // bucket's staging base == row_off at bucket start
    }
    __syncthreads();
#pragma unroll
    for (int i = 0; i < 32; i++) {
        if (meta[i] >= 0) {
            int b = meta[i] >> 13, r = meta[i] & 8191;
            staging[basepos[b] + r] = sv[i];
        }
    }
}

// fill pass 2: one WG per bucket; rank via LDS counters; writes stay in the
// bucket's contiguous csr region (single-WG ownership -> full-line writebacks).
__global__ void fill2_kernel(const int* __restrict__ row_off,
                             const unsigned int* __restrict__ staging,
                             int* __restrict__ csr_src, int n_nodes) {
    __shared__ int cnt[512];
    __shared__ int off[513];
    int t = threadIdx.x;
    int node0 = blockIdx.x << BSHIFT;
    int nn = min(512, n_nodes - node0);
    for (int i = t; i < 512; i += 256) cnt[i] = 0;
    for (int i = t; i <= nn; i += 256) off[i] = row_off[node0 + i];
    __syncthreads();
    int base = off[0], end = off[nn];
    for (int i = base + t; i < end; i += 256) {
        unsigned int w = staging[i];
        int s = (int)(w & 0x1FFFFu);
        int dl = (int)(w >> 17);
        int r = atomicAdd(&cnt[dl], 1);
        csr_src[off[dl] + r] = s;
    }
}

// One wave per node: count distinct incoming sources (!= self) in the CSR row.
// norm = 1 / (1 + distinct)   [the +1 is the I-diagonal of M = I + A^T]
__global__ void norm_dedup_kernel(const int* __restrict__ row_off,
                                  const int* __restrict__ csr_src,
                                  float* __restrict__ norm, int n_nodes) {
    int t = threadIdx.x;
    int node = blockIdx.x * 4 + (t >> 6);
    int lane = t & 63;
    if (node >= n_nodes) return;
    int e0 = row_off[node], e1 = row_off[node + 1];
    int count = 0;
    for (int base = e0; base < e1; base += 64) {
        int idx = base + lane;
        int v = (idx < e1) ? csr_src[idx] : -1;
        bool dup = false;
        for (int j = 0; j < 64; j++) {
            int vj = __shfl(v, j);
            if (j < lane && vj == v) dup = true;
        }
        bool cand = (idx < e1) && (v != node) && !dup;
        if (cand && base > e0) {
            for (int j = e0; j < base; j++) {
                if (csr_src[j] == v) { cand = false; break; }
            }
        }
        count += cand ? 1 : 0;
    }
    for (int off = 32; off; off >>= 1) count += __shfl_xor(count, off);
    if (lane == 0) norm[node] = 1.0f / (1.0f + (float)count);
}

// out[n, c] = b[c] + sum_k x[n, k] * w[k, c];  64 output channels, K in {128, 64}
template <int K>
__global__ void lin_kernel(const float* __restrict__ x, const float* __restrict__ w,
                           const float* __restrict__ b, float* __restrict__ out, int n_nodes) {
    __shared__ float xs[4][K];
    int t = threadIdx.x;
    int node0 = blockIdx.x * 4;
    for (int i = t; i < 4 * K; i += 256) {
        int n = i / K, k = i % K;
        int nn = node0 + n;
        xs[n][k] = (nn < n_nodes) ? x[nn * K + k] : 0.0f;
    }
    __syncthreads();
    int nl = t >> 6, c = t & 63;
    int node = node0 + nl;
    float acc = b[c];
#pragma unroll 8
    for (int k = 0; k < K; k++) acc += xs[nl][k] * w[k * 64 + c];
    if (node < n_nodes) out[node * 64 + c] = acc;
}

// 8-wide-unrolled CSR gather-sum for one node (lane = channel).
__device__ __forceinline__ float gather_row_sum(const float* __restrict__ lin,
                                                const int* __restrict__ csr_src,
                                                int e0, int e1, int c) {
    float acc = 0.0f;
    int e = e0;
    for (; e + 8 <= e1; e += 8) {
        int s0 = csr_src[e + 0], s1 = csr_src[e + 1];
        int s2 = csr_src[e + 2], s3 = csr_src[e + 3];
        int s4 = csr_src[e + 4], s5 = csr_src[e + 5];
        int s6 = csr_src[e + 6], s7 = csr_src[e + 7];
        float v0 = lin[s0 * 64 + c], v1 = lin[s1 * 64 + c];
        float v2 = lin[s2 * 64 + c], v3 = lin[s3 * 64 + c];
        float v4 = lin[s4 * 64 + c], v5 = lin[s5 * 64 + c];
        float v6 = lin[s6 * 64 + c], v7 = lin[s7 * 64 + c];
        acc += ((v0 + v1) + (v2 + v3)) + ((v4 + v5) + (v6 + v7));
    }
    if (e + 4 <= e1) {
        int s0 = csr_src[e + 0], s1 = csr_src[e + 1];
        int s2 = csr_src[e + 2], s3 = csr_src[e + 3];
        float v0 = lin[s0 * 64 + c], v1 = lin[s1 * 64 + c];
        float v2 = lin[s2 * 64 + c], v3 = lin[s3 * 64 + c];
        acc += (v0 + v1) + (v2 + v3);
        e += 4;
    }
    for (; e < e1; e++) acc += lin[csr_src[e] * 64 + c];
    return acc;
}

// One wave per node: CSR gather-sum + PAN combine + relu (layer 1).
__global__ void agg_h_kernel(const float* __restrict__ lin, const int* __restrict__ row_off,
                             const int* __restrict__ csr_src, const float* __restrict__ norm,
                             const float* __restrict__ wpan, float* __restrict__ out,
                             int n_nodes) {
    int t = threadIdx.x;
    int node = blockIdx.x * 4 + (t >> 6);
    int c = t & 63;
    if (node >= n_nodes) return;
    int e0 = row_off[node], e1 = row_off[node + 1];
    float acc = gather_row_sum(lin, csr_src, e0, e1, c);
    float w0 = wpan[0];
    float w01 = wpan[0] * wpan[1];
    float v = norm[node] * (w0 * lin[node * 64 + c] + w01 * acc);
    out[node * 64 + c] = fmaxf(v, 0.0f);
}

// Layer 2 aggregate fused with the edge-head projection:
// pq[n] = {h2[n]@wc[0:64,0], h2[n]@wc[0:64,1], h2[n]@wc[64:128,0], h2[n]@wc[64:128,1]}
__global__ void agg_pq_kernel(const float* __restrict__ lin, const int* __restrict__ row_off,
                              const int* __restrict__ csr_src, const float* __restrict__ norm,
                              const float* __restrict__ wpan, const float* __restrict__ wc,
                              float* __restrict__ pq, int n_nodes) {
    int t = threadIdx.x;
    int node = blockIdx.x * 4 + (t >> 6);
    int c = t & 63;
    if (node >= n_nodes) return;
    int e0 = row_off[node], e1 = row_off[node + 1];
    float acc = gather_row_sum(lin, csr_src, e0, e1, c);
    float w0 = wpan[0];
    float w01 = wpan[0] * wpan[1];
    float v = norm[node] * (w0 * lin[node * 64 + c] + w01 * acc);  // h2[node, c]
    float p0 = v * wc[c * 2 + 0];
    float p1 = v * wc[c * 2 + 1];
    float q0 = v * wc[128 + c * 2 + 0];
    float q1 = v * wc[128 + c * 2 + 1];
    for (int off = 32; off; off >>= 1) {
        p0 += __shfl_xor(p0, off);
        p1 += __shfl_xor(p1, off);
        q0 += __shfl_xor(q0, off);
        q1 += __shfl_xor(q1, off);
    }
    if (c == 0) {
        float4 o = make_float4(p0, p1, q0, q1);
        *(float4*)(pq + node * 4) = o;
    }
}

__global__ void edge_out_kernel(const int* __restrict__ src, const int* __restrict__ dst,
                                const float* __restrict__ pq, const float* __restrict__ bc,
                                float* __restrict__ out, int n_edges) {
    int e = blockIdx.x * blockDim.x + threadIdx.x;
    if (e >= n_edges) return;
    int r = src[e], c = dst[e];
    float2 p = *(const float2*)(pq + r * 4);
    float2 q = *(const float2*)(pq + c * 4 + 2);
    float2 o = make_float2(p.x + q.x + bc[0], p.y + q.y + bc[1]);
    *(float2*)(out + e * 2) = o;
}

extern "C" void kernel_launch(void* const* d_in, const int* in_sizes, int n_in,
                              void* d_out, int out_size, void* d_ws, size_t ws_size,
                              hipStream_t stream) {
    const float* x      = (const float*)d_in[0];
    const int*   eidx   = (const int*)d_in[1];
    const float* w1_lin = (const float*)d_in[2];
    const float* b1_lin = (const float*)d_in[3];
    const float* w1_pan = (const float*)d_in[4];
    const float* w2_lin = (const float*)d_in[5];
    const float* b2_lin = (const float*)d_in[6];
    const float* w2_pan = (const float*)d_in[7];
    const float* wc     = (const float*)d_in[8];
    const float* bc     = (const float*)d_in[9];
    float* out = (float*)d_out;

    const int* src = eidx;           // edge_index[0]
    const int* dst = eidx + NEDGES;  // edge_index[1]

    // ---- workspace carve-up (all 256B-aligned) ----
    char* ws = (char*)d_ws;
    size_t off = 0;
    auto carve = [&](size_t bytes) {
        char* p = ws + off;
        off = (off + bytes + 255) & ~(size_t)255;
        return p;
    };
    // deg + bucket_fill adjacent -> one memset covers both
    int*   deg      = (int*)carve((size_t)NNODES * 4);
    int*   bucket_fill = (int*)(ws);  // placed right after deg via carve below
    bucket_fill     = (int*)carve((size_t)NB * 4);
    int*   row_off  = (int*)carve((size_t)(NNODES + 1) * 4);
    int*   partial  = (int*)carve((size_t)128 * 4);
    unsigned int* staging = (unsigned int*)carve((size_t)NEDGES * 4);
    int*   csr_src  = (int*)carve((size_t)NEDGES * 4);
    float* nrm      = (float*)carve((size_t)NNODES * 4);
    float* bufA     = (float*)carve((size_t)NNODES * HIDC * 4);  // 25.6 MB
    float* bufB     = (float*)carve((size_t)NNODES * HIDC * 4);  // 25.6 MB
    float* pq       = (float*)carve((size_t)NNODES * 4 * 4);
    (void)ws_size; (void)in_sizes; (void)n_in; (void)out_size;

    const int nchunks = (NNODES + 1023) / 1024;  // 98

    // zero deg (400 KB) + bucket_fill (NB ints, contiguous after deg's 256B pad)
    hipMemsetAsync(deg, 0, ((size_t)NNODES * 4 + 255 + (size_t)NB * 4 + 255) & ~(size_t)255,
                   stream);

    // in-degree counts
    count_kernel<<<NEDGES / 256, 256, 0, stream>>>(dst, deg, NEDGES);

    // CSR row offsets (exclusive scan)
    scan1_kernel<<<nchunks, 256, 0, stream>>>(deg, row_off, partial, NNODES);
    scan2_kernel<<<1, 128, 0, stream>>>(partial, row_off, nchunks, NNODES);
    scan3_kernel<<<(NNODES + 255) / 256, 256, 0, stream>>>(row_off, partial, NNODES);

    // CSR adjacency fill: binned two-pass scatter (full-line writebacks)
    fill1_kernel<<<(NEDGES + TILE - 1) / TILE, 256, 0, stream>>>(src, dst, row_off,
                                                                 bucket_fill, staging, NEDGES);
    fill2_kernel<<<NB, 256, 0, stream>>>(row_off, staging, csr_src, NNODES);

    // norm = 1 / rowcount(I + A^T) via per-row dedup
    norm_dedup_kernel<<<(NNODES + 3) / 4, 256, 0, stream>>>(row_off, csr_src, nrm, NNODES);

    // layer 1: lin -> aggregate -> combine + relu
    lin_kernel<INC><<<NNODES / 4, 256, 0, stream>>>(x, w1_lin, b1_lin, bufA, NNODES);
    agg_h_kernel<<<NNODES / 4, 256, 0, stream>>>(bufA, row_off, csr_src, nrm, w1_pan, bufB,
                                                 NNODES);

    // layer 2: lin -> aggregate fused with edge-head projection
    lin_kernel<HIDC><<<NNODES / 4, 256, 0, stream>>>(bufB, w2_lin, b2_lin, bufA, NNODES);
    agg_pq_kernel<<<NNODES / 4, 256, 0, stream>>>(bufA, row_off, csr_src, nrm, w2_pan, wc,
                                                  pq, NNODES);

    // edge head: out[e] = p[src[e]] + q[dst[e]] + bc
    edge_out_kernel<<<NEDGES / 256, 256, 0, stream>>>(src, dst, pq, bc, out, NEDGES);
}

// Round 5
// 484.187 us; speedup vs baseline: 2.0026x; 1.1924x over previous
//
#include <hip/hip_runtime.h>

#define NNODES 100000
#define NEDGES 1600000
#define INC 128
#define HIDC 64
#define BSHIFT 9                      // 512 nodes per bucket
#define NB ((NNODES + 511) / 512)     // 196 buckets
#define TILE 8192                     // edges per fill1 workgroup (32/thread)

// Per edge: in-degree count (for CSR).
__global__ void count_kernel(const int* __restrict__ dst, int* __restrict__ deg, int n_edges) {
    int e = blockIdx.x * blockDim.x + threadIdx.x;
    if (e >= n_edges) return;
    atomicAdd(&deg[dst[e]], 1);
}

// Exclusive scan of deg -> row_off, 1024-element chunks.
__global__ void scan1_kernel(const int* __restrict__ deg, int* __restrict__ row_off,
                             int* __restrict__ partial, int n) {
    __shared__ int sdata[256];
    int t = threadIdx.x;
    int base = blockIdx.x * 1024 + t * 4;
    int v0 = (base + 0 < n) ? deg[base + 0] : 0;
    int v1 = (base + 1 < n) ? deg[base + 1] : 0;
    int v2 = (base + 2 < n) ? deg[base + 2] : 0;
    int v3 = (base + 3 < n) ? deg[base + 3] : 0;
    int sum = v0 + v1 + v2 + v3;
    sdata[t] = sum;
    __syncthreads();
    for (int off = 1; off < 256; off <<= 1) {
        int x = (t >= off) ? sdata[t - off] : 0;
        __syncthreads();
        sdata[t] += x;
        __syncthreads();
    }
    int excl = sdata[t] - sum;
    if (base + 0 < n) row_off[base + 0] = excl;
    if (base + 1 < n) row_off[base + 1] = excl + v0;
    if (base + 2 < n) row_off[base + 2] = excl + v0 + v1;
    if (base + 3 < n) row_off[base + 3] = excl + v0 + v1 + v2;
    if (t == 255) partial[blockIdx.x] = sdata[255];
}

// Scan the 98 chunk totals in parallel (one 128-thread block).
__global__ void scan2_kernel(int* __restrict__ partial, int* __restrict__ row_off,
                             int nchunks, int n) {
    __shared__ int sdata[128];
    int t = threadIdx.x;
    int v = (t < nchunks) ? partial[t] : 0;
    sdata[t] = v;
    __syncthreads();
    for (int off = 1; off < 128; off <<= 1) {
        int x = (t >= off) ? sdata[t - off] : 0;
        __syncthreads();
        sdata[t] += x;
        __syncthreads();
    }
    if (t < nchunks) partial[t] = sdata[t] - v;  // exclusive chunk offset
    if (t == 127) row_off[n] = sdata[127];       // grand total
}

__global__ void scan3_kernel(int* __restrict__ row_off, const int* __restrict__ partial, int n) {
    int i = blockIdx.x * blockDim.x + threadIdx.x;
    if (i >= n) return;
    row_off[i] += partial[i >> 10];
}

// fill pass 1: bin edges into bucket-contiguous staging chunks.
// staged word = (dst & 511) << 17 | src   (src < 2^17, dlocal < 2^9)
__global__ void fill1_kernel(const int* __restrict__ src, const int* __restrict__ dst,
                             const int* __restrict__ row_off, int* __restrict__ bucket_fill,
                             unsigned int* __restrict__ staging, int n_edges) {
    __shared__ int cnt[NB];
    __shared__ int basepos[NB];
    int t = threadIdx.x;
    for (int i = t; i < NB; i += 256) cnt[i] = 0;
    __syncthreads();
    int tile0 = blockIdx.x * TILE;
    unsigned int sv[32];
    int meta[32];
#pragma unroll
    for (int i = 0; i < 32; i++) {
        int e = tile0 + i * 256 + t;
        meta[i] = -1;
        sv[i] = 0;
        if (e < n_edges) {
            int s = src[e], d = dst[e];
            int b = d >> BSHIFT;
            int r = atomicAdd(&cnt[b], 1);      // rank within (tile, bucket); < TILE
            meta[i] = (b << 13) | r;
            sv[i] = ((unsigned)(d & 511) << 17) | (unsigned)s;
        }
    }
    __syncthreads();
    for (int i = t; i < NB; i += 256) {
        int c = cnt[i];
        int g = (c > 0) ? atomicAdd(&bucket_fill[i], c) : 0;
        basepos[i] = row_off[i << BSHIFT] + g;  // bucket's staging base == row_off at bucket start
    }
    __syncthreads();
#pragma unroll
    for (int i = 0; i < 32; i++) {
        if (meta[i] >= 0) {
            int b = meta[i] >> 13, r = meta[i] & 8191;
            staging[basepos[b] + r] = sv[i];
        }
    }
}

// fill pass 2: one WG per bucket; rank via LDS counters; writes stay in the
// bucket's contiguous csr region (single-WG ownership -> full-line writebacks).
__global__ void fill2_kernel(const int* __restrict__ row_off,
                             const unsigned int* __restrict__ staging,
                             int* __restrict__ csr_src, int n_nodes) {
    __shared__ int cnt[512];
    __shared__ int off[513];
    int t = threadIdx.x;
    int node0 = blockIdx.x << BSHIFT;
    int nn = min(512, n_nodes - node0);
    for (int i = t; i < 512; i += 256) cnt[i] = 0;
    for (int i = t; i <= nn; i += 256) off[i] = row_off[node0 + i];
    __syncthreads();
    int base = off[0], end = off[nn];
    for (int i = base + t; i < end; i += 256) {
        unsigned int w = staging[i];
        int s = (int)(w & 0x1FFFFu);
        int dl = (int)(w >> 17);
        int r = atomicAdd(&cnt[dl], 1);
        csr_src[off[dl] + r] = s;
    }
}

// One wave per node: count distinct incoming sources (!= self) in the CSR row.
// norm = 1 / (1 + distinct)   [the +1 is the I-diagonal of M = I + A^T]
__global__ void norm_dedup_kernel(const int* __restrict__ row_off,
                                  const int* __restrict__ csr_src,
                                  float* __restrict__ norm, int n_nodes) {
    int t = threadIdx.x;
    int node = blockIdx.x * 4 + (t >> 6);
    int lane = t & 63;
    if (node >= n_nodes) return;
    int e0 = row_off[node], e1 = row_off[node + 1];
    int count = 0;
    for (int base = e0; base < e1; base += 64) {
        int idx = base + lane;
        int v = (idx < e1) ? csr_src[idx] : -1;
        bool dup = false;
        for (int j = 0; j < 64; j++) {
            int vj = __shfl(v, j);
            if (j < lane && vj == v) dup = true;
        }
        bool cand = (idx < e1) && (v != node) && !dup;
        if (cand && base > e0) {
            for (int j = e0; j < base; j++) {
                if (csr_src[j] == v) { cand = false; break; }
            }
        }
        count += cand ? 1 : 0;
    }
    for (int off = 32; off; off >>= 1) count += __shfl_xor(count, off);
    if (lane == 0) norm[node] = 1.0f / (1.0f + (float)count);
}

// Register-tiled GEMM: out[64-node tile, 64 ch] = x @ w + b.
// Each thread: 4 nodes x 4 channels. x tile in LDS (padded, 2-way-free banks);
// w streamed as float4 through L1 (32 KB, block-invariant, 16-lane broadcast).
template <int K>
__global__ __launch_bounds__(256) void lin_kernel(const float* __restrict__ x,
                                                  const float* __restrict__ w,
                                                  const float* __restrict__ b,
                                                  float* __restrict__ out, int n_nodes) {
    __shared__ float xs[64][K + 4];
    int t = threadIdx.x;
    int node0 = blockIdx.x * 64;
    int nn = min(64, n_nodes - node0);
    constexpr int C4 = K / 4;
    for (int idx = t; idx < 64 * C4; idx += 256) {
        int row = idx / C4, c4 = idx % C4;
        float4 v = make_float4(0.f, 0.f, 0.f, 0.f);
        if (row < nn) v = *(const float4*)(x + (size_t)(node0 + row) * K + c4 * 4);
        *(float4*)(&xs[row][c4 * 4]) = v;
    }
    __syncthreads();
    int tn = t >> 4, tc = t & 15;
    int n0 = tn * 4, c0 = tc * 4;
    float4 bb = *(const float4*)(b + c0);
    float acc[4][4];
#pragma unroll
    for (int i = 0; i < 4; i++) {
        acc[i][0] = bb.x; acc[i][1] = bb.y; acc[i][2] = bb.z; acc[i][3] = bb.w;
    }
#pragma unroll 4
    for (int k = 0; k < K; k += 4) {
        float xr[4][4], wr[4][4];
#pragma unroll
        for (int i = 0; i < 4; i++)
            *(float4*)&xr[i][0] = *(const float4*)(&xs[n0 + i][k]);
#pragma unroll
        for (int j = 0; j < 4; j++)
            *(float4*)&wr[j][0] = *(const float4*)(w + (size_t)(k + j) * 64 + c0);
#pragma unroll
        for (int i = 0; i < 4; i++)
#pragma unroll
            for (int kk = 0; kk < 4; kk++)
#pragma unroll
                for (int j = 0; j < 4; j++)
                    acc[i][j] += xr[i][kk] * wr[kk][j];
    }
#pragma unroll
    for (int i = 0; i < 4; i++) {
        int node = node0 + n0 + i;
        if (node < n_nodes) {
            float4 v = make_float4(acc[i][0], acc[i][1], acc[i][2], acc[i][3]);
            *(float4*)(out + (size_t)node * 64 + c0) = v;
        }
    }
}

// 8-wide-unrolled CSR gather-sum for one node (lane = channel).
__device__ __forceinline__ float gather_row_sum(const float* __restrict__ lin,
                                                const int* __restrict__ csr_src,
                                                int e0, int e1, int c) {
    float acc = 0.0f;
    int e = e0;
    for (; e + 8 <= e1; e += 8) {
        int s0 = csr_src[e + 0], s1 = csr_src[e + 1];
        int s2 = csr_src[e + 2], s3 = csr_src[e + 3];
        int s4 = csr_src[e + 4], s5 = csr_src[e + 5];
        int s6 = csr_src[e + 6], s7 = csr_src[e + 7];
        float v0 = lin[s0 * 64 + c], v1 = lin[s1 * 64 + c];
        float v2 = lin[s2 * 64 + c], v3 = lin[s3 * 64 + c];
        float v4 = lin[s4 * 64 + c], v5 = lin[s5 * 64 + c];
        float v6 = lin[s6 * 64 + c], v7 = lin[s7 * 64 + c];
        acc += ((v0 + v1) + (v2 + v3)) + ((v4 + v5) + (v6 + v7));
    }
    if (e + 4 <= e1) {
        int s0 = csr_src[e + 0], s1 = csr_src[e + 1];
        int s2 = csr_src[e + 2], s3 = csr_src[e + 3];
        float v0 = lin[s0 * 64 + c], v1 = lin[s1 * 64 + c];
        float v2 = lin[s2 * 64 + c], v3 = lin[s3 * 64 + c];
        acc += (v0 + v1) + (v2 + v3);
        e += 4;
    }
    for (; e < e1; e++) acc += lin[csr_src[e] * 64 + c];
    return acc;
}

// One wave per node: CSR gather-sum + PAN combine + relu (layer 1).
__global__ void agg_h_kernel(const float* __restrict__ lin, const int* __restrict__ row_off,
                             const int* __restrict__ csr_src, const float* __restrict__ norm,
                             const float* __restrict__ wpan, float* __restrict__ out,
                             int n_nodes) {
    int t = threadIdx.x;
    int node = blockIdx.x * 4 + (t >> 6);
    int c = t & 63;
    if (node >= n_nodes) return;
    int e0 = row_off[node], e1 = row_off[node + 1];
    float acc = gather_row_sum(lin, csr_src, e0, e1, c);
    float w0 = wpan[0];
    float w01 = wpan[0] * wpan[1];
    float v = norm[node] * (w0 * lin[node * 64 + c] + w01 * acc);
    out[node * 64 + c] = fmaxf(v, 0.0f);
}

// Layer 2 aggregate fused with the edge-head projection:
// pq[n] = {h2[n]@wc[0:64,0], h2[n]@wc[0:64,1], h2[n]@wc[64:128,0], h2[n]@wc[64:128,1]}
__global__ void agg_pq_kernel(const float* __restrict__ lin, const int* __restrict__ row_off,
                              const int* __restrict__ csr_src, const float* __restrict__ norm,
                              const float* __restrict__ wpan, const float* __restrict__ wc,
                              float* __restrict__ pq, int n_nodes) {
    int t = threadIdx.x;
    int node = blockIdx.x * 4 + (t >> 6);
    int c = t & 63;
    if (node >= n_nodes) return;
    int e0 = row_off[node], e1 = row_off[node + 1];
    float acc = gather_row_sum(lin, csr_src, e0, e1, c);
    float w0 = wpan[0];
    float w01 = wpan[0] * wpan[1];
    float v = norm[node] * (w0 * lin[node * 64 + c] + w01 * acc);  // h2[node, c]
    float p0 = v * wc[c * 2 + 0];
    float p1 = v * wc[c * 2 + 1];
    float q0 = v * wc[128 + c * 2 + 0];
    float q1 = v * wc[128 + c * 2 + 1];
    for (int off = 32; off; off >>= 1) {
        p0 += __shfl_xor(p0, off);
        p1 += __shfl_xor(p1, off);
        q0 += __shfl_xor(q0, off);
        q1 += __shfl_xor(q1, off);
    }
    if (c == 0) {
        float4 o = make_float4(p0, p1, q0, q1);
        *(float4*)(pq + node * 4) = o;
    }
}

__global__ void edge_out_kernel(const int* __restrict__ src, const int* __restrict__ dst,
                                const float* __restrict__ pq, const float* __restrict__ bc,
                                float* __restrict__ out, int n_edges) {
    int e = blockIdx.x * blockDim.x + threadIdx.x;
    if (e >= n_edges) return;
    int r = src[e], c = dst[e];
    float2 p = *(const float2*)(pq + r * 4);
    float2 q = *(const float2*)(pq + c * 4 + 2);
    float2 o = make_float2(p.x + q.x + bc[0], p.y + q.y + bc[1]);
    *(float2*)(out + e * 2) = o;
}

extern "C" void kernel_launch(void* const* d_in, const int* in_sizes, int n_in,
                              void* d_out, int out_size, void* d_ws, size_t ws_size,
                              hipStream_t stream) {
    const float* x      = (const float*)d_in[0];
    const int*   eidx   = (const int*)d_in[1];
    const float* w1_lin = (const float*)d_in[2];
    const float* b1_lin = (const float*)d_in[3];
    const float* w1_pan = (const float*)d_in[4];
    const float* w2_lin = (const float*)d_in[5];
    const float* b2_lin = (const float*)d_in[6];
    const float* w2_pan = (const float*)d_in[7];
    const float* wc     = (const float*)d_in[8];
    const float* bc     = (const float*)d_in[9];
    float* out = (float*)d_out;

    const int* src = eidx;           // edge_index[0]
    const int* dst = eidx + NEDGES;  // edge_index[1]

    // ---- workspace carve-up (all 256B-aligned) ----
    char* ws = (char*)d_ws;
    size_t off = 0;
    auto carve = [&](size_t bytes) {
        char* p = ws + off;
        off = (off + bytes + 255) & ~(size_t)255;
        return p;
    };
    int*   deg      = (int*)carve((size_t)NNODES * 4);
    int*   bucket_fill = (int*)carve((size_t)NB * 4);
    int*   row_off  = (int*)carve((size_t)(NNODES + 1) * 4);
    int*   partial  = (int*)carve((size_t)128 * 4);
    unsigned int* staging = (unsigned int*)carve((size_t)NEDGES * 4);
    int*   csr_src  = (int*)carve((size_t)NEDGES * 4);
    float* nrm      = (float*)carve((size_t)NNODES * 4);
    float* bufA     = (float*)carve((size_t)NNODES * HIDC * 4);  // 25.6 MB
    float* bufB     = (float*)carve((size_t)NNODES * HIDC * 4);  // 25.6 MB
    float* pq       = (float*)carve((size_t)NNODES * 4 * 4);
    (void)ws_size; (void)in_sizes; (void)n_in; (void)out_size;

    const int nchunks = (NNODES + 1023) / 1024;  // 98

    // zero deg (400 KB) + bucket_fill (contiguous after deg's 256B pad)
    hipMemsetAsync(deg, 0, ((size_t)NNODES * 4 + 255 + (size_t)NB * 4 + 255) & ~(size_t)255,
                   stream);

    // in-degree counts
    count_kernel<<<NEDGES / 256, 256, 0, stream>>>(dst, deg, NEDGES);

    // CSR row offsets (exclusive scan)
    scan1_kernel<<<nchunks, 256, 0, stream>>>(deg, row_off, partial, NNODES);
    scan2_kernel<<<1, 128, 0, stream>>>(partial, row_off, nchunks, NNODES);
    scan3_kernel<<<(NNODES + 255) / 256, 256, 0, stream>>>(row_off, partial, NNODES);

    // CSR adjacency fill: binned two-pass scatter (full-line writebacks)
    fill1_kernel<<<(NEDGES + TILE - 1) / TILE, 256, 0, stream>>>(src, dst, row_off,
                                                                 bucket_fill, staging, NEDGES);
    fill2_kernel<<<NB, 256, 0, stream>>>(row_off, staging, csr_src, NNODES);

    // norm = 1 / rowcount(I + A^T) via per-row dedup
    norm_dedup_kernel<<<(NNODES + 3) / 4, 256, 0, stream>>>(row_off, csr_src, nrm, NNODES);

    // layer 1: lin -> aggregate -> combine + relu
    lin_kernel<INC><<<(NNODES + 63) / 64, 256, 0, stream>>>(x, w1_lin, b1_lin, bufA, NNODES);
    agg_h_kernel<<<NNODES / 4, 256, 0, stream>>>(bufA, row_off, csr_src, nrm, w1_pan, bufB,
                                                 NNODES);

    // layer 2: lin -> aggregate fused with edge-head projection
    lin_kernel<HIDC><<<(NNODES + 63) / 64, 256, 0, stream>>>(bufB, w2_lin, b2_lin, bufA, NNODES);
    agg_pq_kernel<<<NNODES / 4, 256, 0, stream>>>(bufA, row_off, csr_src, nrm, w2_pan, wc,
                                                  pq, NNODES);

    // edge head: out[e] = p[src[e]] + q[dst[e]] + bc
    edge_out_kernel<<<NEDGES / 256, 256, 0, stream>>>(src, dst, pq, bc, out, NEDGES);
}

// Round 6
// 440.335 us; speedup vs baseline: 2.2021x; 1.0996x over previous
//
#include <hip/hip_runtime.h>

#define NNODES 100000
#define NEDGES 1600000
#define INC 128
#define HIDC 64
#define BSHIFT 9                      // 512 nodes per bucket
#define NB ((NNODES + 511) / 512)     // 196 buckets
#define TILE 8192                     // edges per fill1 workgroup (32/thread)
#define HSLOTS 16384                  // LDS hash slots in fill2 (64 KB)

// Per edge: in-degree count (for CSR).
__global__ void count_kernel(const int* __restrict__ dst, int* __restrict__ deg, int n_edges) {
    int e = blockIdx.x * blockDim.x + threadIdx.x;
    if (e >= n_edges) return;
    atomicAdd(&deg[dst[e]], 1);
}

// Exclusive scan of deg -> row_off, 1024-element chunks.
__global__ void scan1_kernel(const int* __restrict__ deg, int* __restrict__ row_off,
                             int* __restrict__ partial, int n) {
    __shared__ int sdata[256];
    int t = threadIdx.x;
    int base = blockIdx.x * 1024 + t * 4;
    int v0 = (base + 0 < n) ? deg[base + 0] : 0;
    int v1 = (base + 1 < n) ? deg[base + 1] : 0;
    int v2 = (base + 2 < n) ? deg[base + 2] : 0;
    int v3 = (base + 3 < n) ? deg[base + 3] : 0;
    int sum = v0 + v1 + v2 + v3;
    sdata[t] = sum;
    __syncthreads();
    for (int off = 1; off < 256; off <<= 1) {
        int x = (t >= off) ? sdata[t - off] : 0;
        __syncthreads();
        sdata[t] += x;
        __syncthreads();
    }
    int excl = sdata[t] - sum;
    if (base + 0 < n) row_off[base + 0] = excl;
    if (base + 1 < n) row_off[base + 1] = excl + v0;
    if (base + 2 < n) row_off[base + 2] = excl + v0 + v1;
    if (base + 3 < n) row_off[base + 3] = excl + v0 + v1 + v2;
    if (t == 255) partial[blockIdx.x] = sdata[255];
}

// Scan the 98 chunk totals in parallel (one 128-thread block).
__global__ void scan2_kernel(int* __restrict__ partial, int* __restrict__ row_off,
                             int nchunks, int n) {
    __shared__ int sdata[128];
    int t = threadIdx.x;
    int v = (t < nchunks) ? partial[t] : 0;
    sdata[t] = v;
    __syncthreads();
    for (int off = 1; off < 128; off <<= 1) {
        int x = (t >= off) ? sdata[t - off] : 0;
        __syncthreads();
        sdata[t] += x;
        __syncthreads();
    }
    if (t < nchunks) partial[t] = sdata[t] - v;  // exclusive chunk offset
    if (t == 127) row_off[n] = sdata[127];       // grand total
}

__global__ void scan3_kernel(int* __restrict__ row_off, const int* __restrict__ partial, int n) {
    int i = blockIdx.x * blockDim.x + threadIdx.x;
    if (i >= n) return;
    row_off[i] += partial[i >> 10];
}

// fill pass 1: bin edges into bucket-contiguous staging chunks.
// staged word = (dst & 511) << 17 | src   (src < 2^17, dlocal < 2^9)
__global__ void fill1_kernel(const int* __restrict__ src, const int* __restrict__ dst,
                             const int* __restrict__ row_off, int* __restrict__ bucket_fill,
                             unsigned int* __restrict__ staging, int n_edges) {
    __shared__ int cnt[NB];
    __shared__ int basepos[NB];
    int t = threadIdx.x;
    for (int i = t; i < NB; i += 256) cnt[i] = 0;
    __syncthreads();
    int tile0 = blockIdx.x * TILE;
    unsigned int sv[32];
    int meta[32];
#pragma unroll
    for (int i = 0; i < 32; i++) {
        int e = tile0 + i * 256 + t;
        meta[i] = -1;
        sv[i] = 0;
        if (e < n_edges) {
            int s = src[e], d = dst[e];
            int b = d >> BSHIFT;
            int r = atomicAdd(&cnt[b], 1);      // rank within (tile, bucket); < TILE
            meta[i] = (b << 13) | r;
            sv[i] = ((unsigned)(d & 511) << 17) | (unsigned)s;
        }
    }
    __syncthreads();
    for (int i = t; i < NB; i += 256) {
        int c = cnt[i];
        int g = (c > 0) ? atomicAdd(&bucket_fill[i], c) : 0;
        basepos[i] = row_off[i << BSHIFT] + g;  // bucket's staging base == row_off at bucket start
    }
    __syncthreads();
#pragma unroll
    for (int i = 0; i < 32; i++) {
        if (meta[i] >= 0) {
            int b = meta[i] >> 13, r = meta[i] & 8191;
            staging[basepos[b] + r] = sv[i];
        }
    }
}

// fill pass 2: one WG per bucket; rank via LDS counters; writes stay in the
// bucket's contiguous csr region. Fused: per-(node,src) dedup via LDS hash ->
// distinct-incoming count -> norm = 1/(1+distinct).
__global__ void fill2_kernel(const int* __restrict__ row_off,
                             const unsigned int* __restrict__ staging,
                             int* __restrict__ csr_src, float* __restrict__ norm,
                             int n_nodes) {
    __shared__ int cnt[512];
    __shared__ int dcount[512];
    __shared__ int off[513];
    __shared__ unsigned int ht[HSLOTS];
    int t = threadIdx.x;
    int node0 = blockIdx.x << BSHIFT;
    int nn = min(512, n_nodes - node0);
    for (int i = t; i < 512; i += 256) { cnt[i] = 0; dcount[i] = 0; }
    for (int i = t; i <= nn; i += 256) off[i] = row_off[node0 + i];
    {   // vectorized sentinel init: 16384 words / 256 threads = 16 uint4
        uint4* h4 = (uint4*)ht;
        uint4 ff = make_uint4(0xFFFFFFFFu, 0xFFFFFFFFu, 0xFFFFFFFFu, 0xFFFFFFFFu);
        for (int i = t; i < HSLOTS / 4; i += 256) h4[i] = ff;
    }
    __syncthreads();
    int base = off[0], end = off[nn];
    for (int i = base + t; i < end; i += 256) {
        unsigned int w = staging[i];
        int s = (int)(w & 0x1FFFFu);
        int dl = (int)(w >> 17);
        int r = atomicAdd(&cnt[dl], 1);
        csr_src[off[dl] + r] = s;
        if (s != node0 + dl) {  // self-loops merge with the I-diagonal
            unsigned int slot = ((w * 2654435761u) >> 12) & (HSLOTS - 1);
            while (true) {
                unsigned int prev = atomicCAS(&ht[slot], 0xFFFFFFFFu, w);
                if (prev == 0xFFFFFFFFu) { atomicAdd(&dcount[dl], 1); break; }
                if (prev == w) break;
                slot = (slot + 1) & (HSLOTS - 1);
            }
        }
    }
    __syncthreads();
    for (int i = t; i < nn; i += 256)
        norm[node0 + i] = 1.0f / (1.0f + (float)dcount[i]);
}

// Register-tiled GEMM: out[64-node tile, 64 ch] = x @ w + b.
// Each thread: 4 nodes x 4 channels. x tile in LDS (padded, 2-way-free banks);
// w streamed as float4 through L1 (32 KB, block-invariant, 16-lane broadcast).
template <int K>
__global__ __launch_bounds__(256) void lin_kernel(const float* __restrict__ x,
                                                  const float* __restrict__ w,
                                                  const float* __restrict__ b,
                                                  float* __restrict__ out, int n_nodes) {
    __shared__ float xs[64][K + 4];
    int t = threadIdx.x;
    int node0 = blockIdx.x * 64;
    int nn = min(64, n_nodes - node0);
    constexpr int C4 = K / 4;
    for (int idx = t; idx < 64 * C4; idx += 256) {
        int row = idx / C4, c4 = idx % C4;
        float4 v = make_float4(0.f, 0.f, 0.f, 0.f);
        if (row < nn) v = *(const float4*)(x + (size_t)(node0 + row) * K + c4 * 4);
        *(float4*)(&xs[row][c4 * 4]) = v;
    }
    __syncthreads();
    int tn = t >> 4, tc = t & 15;
    int n0 = tn * 4, c0 = tc * 4;
    float4 bb = *(const float4*)(b + c0);
    float acc[4][4];
#pragma unroll
    for (int i = 0; i < 4; i++) {
        acc[i][0] = bb.x; acc[i][1] = bb.y; acc[i][2] = bb.z; acc[i][3] = bb.w;
    }
#pragma unroll 4
    for (int k = 0; k < K; k += 4) {
        float xr[4][4], wr[4][4];
#pragma unroll
        for (int i = 0; i < 4; i++)
            *(float4*)&xr[i][0] = *(const float4*)(&xs[n0 + i][k]);
#pragma unroll
        for (int j = 0; j < 4; j++)
            *(float4*)&wr[j][0] = *(const float4*)(w + (size_t)(k + j) * 64 + c0);
#pragma unroll
        for (int i = 0; i < 4; i++)
#pragma unroll
            for (int kk = 0; kk < 4; kk++)
#pragma unroll
                for (int j = 0; j < 4; j++)
                    acc[i][j] += xr[i][kk] * wr[kk][j];
    }
#pragma unroll
    for (int i = 0; i < 4; i++) {
        int node = node0 + n0 + i;
        if (node < n_nodes) {
            float4 v = make_float4(acc[i][0], acc[i][1], acc[i][2], acc[i][3]);
            *(float4*)(out + (size_t)node * 64 + c0) = v;
        }
    }
}

// 8-wide-unrolled CSR gather-sum for one node (lane = channel).
__device__ __forceinline__ float gather_row_sum(const float* __restrict__ lin,
                                                const int* __restrict__ csr_src,
                                                int e0, int e1, int c) {
    float acc = 0.0f;
    int e = e0;
    for (; e + 8 <= e1; e += 8) {
        int s0 = csr_src[e + 0], s1 = csr_src[e + 1];
        int s2 = csr_src[e + 2], s3 = csr_src[e + 3];
        int s4 = csr_src[e + 4], s5 = csr_src[e + 5];
        int s6 = csr_src[e + 6], s7 = csr_src[e + 7];
        float v0 = lin[s0 * 64 + c], v1 = lin[s1 * 64 + c];
        float v2 = lin[s2 * 64 + c], v3 = lin[s3 * 64 + c];
        float v4 = lin[s4 * 64 + c], v5 = lin[s5 * 64 + c];
        float v6 = lin[s6 * 64 + c], v7 = lin[s7 * 64 + c];
        acc += ((v0 + v1) + (v2 + v3)) + ((v4 + v5) + (v6 + v7));
    }
    if (e + 4 <= e1) {
        int s0 = csr_src[e + 0], s1 = csr_src[e + 1];
        int s2 = csr_src[e + 2], s3 = csr_src[e + 3];
        float v0 = lin[s0 * 64 + c], v1 = lin[s1 * 64 + c];
        float v2 = lin[s2 * 64 + c], v3 = lin[s3 * 64 + c];
        acc += (v0 + v1) + (v2 + v3);
        e += 4;
    }
    for (; e < e1; e++) acc += lin[csr_src[e] * 64 + c];
    return acc;
}

// One wave per node: CSR gather-sum + PAN combine + relu (layer 1).
__global__ void agg_h_kernel(const float* __restrict__ lin, const int* __restrict__ row_off,
                             const int* __restrict__ csr_src, const float* __restrict__ norm,
                             const float* __restrict__ wpan, float* __restrict__ out,
                             int n_nodes) {
    int t = threadIdx.x;
    int node = blockIdx.x * 4 + (t >> 6);
    int c = t & 63;
    if (node >= n_nodes) return;
    int e0 = row_off[node], e1 = row_off[node + 1];
    float acc = gather_row_sum(lin, csr_src, e0, e1, c);
    float w0 = wpan[0];
    float w01 = wpan[0] * wpan[1];
    float v = norm[node] * (w0 * lin[node * 64 + c] + w01 * acc);
    out[node * 64 + c] = fmaxf(v, 0.0f);
}

// Layer 2 aggregate fused with the edge-head projection:
// pq[n] = {h2[n]@wc[0:64,0], h2[n]@wc[0:64,1], h2[n]@wc[64:128,0], h2[n]@wc[64:128,1]}
__global__ void agg_pq_kernel(const float* __restrict__ lin, const int* __restrict__ row_off,
                              const int* __restrict__ csr_src, const float* __restrict__ norm,
                              const float* __restrict__ wpan, const float* __restrict__ wc,
                              float* __restrict__ pq, int n_nodes) {
    int t = threadIdx.x;
    int node = blockIdx.x * 4 + (t >> 6);
    int c = t & 63;
    if (node >= n_nodes) return;
    int e0 = row_off[node], e1 = row_off[node + 1];
    float acc = gather_row_sum(lin, csr_src, e0, e1, c);
    float w0 = wpan[0];
    float w01 = wpan[0] * wpan[1];
    float v = norm[node] * (w0 * lin[node * 64 + c] + w01 * acc);  // h2[node, c]
    float p0 = v * wc[c * 2 + 0];
    float p1 = v * wc[c * 2 + 1];
    float q0 = v * wc[128 + c * 2 + 0];
    float q1 = v * wc[128 + c * 2 + 1];
    for (int off = 32; off; off >>= 1) {
        p0 += __shfl_xor(p0, off);
        p1 += __shfl_xor(p1, off);
        q0 += __shfl_xor(q0, off);
        q1 += __shfl_xor(q1, off);
    }
    if (c == 0) {
        float4 o = make_float4(p0, p1, q0, q1);
        *(float4*)(pq + node * 4) = o;
    }
}

__global__ void edge_out_kernel(const int* __restrict__ src, const int* __restrict__ dst,
                                const float* __restrict__ pq, const float* __restrict__ bc,
                                float* __restrict__ out, int n_edges) {
    int e = blockIdx.x * blockDim.x + threadIdx.x;
    if (e >= n_edges) return;
    int r = src[e], c = dst[e];
    float2 p = *(const float2*)(pq + r * 4);
    float2 q = *(const float2*)(pq + c * 4 + 2);
    float2 o = make_float2(p.x + q.x + bc[0], p.y + q.y + bc[1]);
    *(float2*)(out + e * 2) = o;
}

extern "C" void kernel_launch(void* const* d_in, const int* in_sizes, int n_in,
                              void* d_out, int out_size, void* d_ws, size_t ws_size,
                              hipStream_t stream) {
    const float* x      = (const float*)d_in[0];
    const int*   eidx   = (const int*)d_in[1];
    const float* w1_lin = (const float*)d_in[2];
    const float* b1_lin = (const float*)d_in[3];
    const float* w1_pan = (const float*)d_in[4];
    const float* w2_lin = (const float*)d_in[5];
    const float* b2_lin = (const float*)d_in[6];
    const float* w2_pan = (const float*)d_in[7];
    const float* wc     = (const float*)d_in[8];
    const float* bc     = (const float*)d_in[9];
    float* out = (float*)d_out;

    const int* src = eidx;           // edge_index[0]
    const int* dst = eidx + NEDGES;  // edge_index[1]

    // ---- workspace carve-up (all 256B-aligned) ----
    char* ws = (char*)d_ws;
    size_t off = 0;
    auto carve = [&](size_t bytes) {
        char* p = ws + off;
        off = (off + bytes + 255) & ~(size_t)255;
        return p;
    };
    int*   deg      = (int*)carve((size_t)NNODES * 4);
    int*   bucket_fill = (int*)carve((size_t)NB * 4);
    int*   row_off  = (int*)carve((size_t)(NNODES + 1) * 4);
    int*   partial  = (int*)carve((size_t)128 * 4);
    unsigned int* staging = (unsigned int*)carve((size_t)NEDGES * 4);
    int*   csr_src  = (int*)carve((size_t)NEDGES * 4);
    float* nrm      = (float*)carve((size_t)NNODES * 4);
    float* bufA     = (float*)carve((size_t)NNODES * HIDC * 4);  // 25.6 MB
    float* bufB     = (float*)carve((size_t)NNODES * HIDC * 4);  // 25.6 MB
    float* pq       = (float*)carve((size_t)NNODES * 4 * 4);
    (void)ws_size; (void)in_sizes; (void)n_in; (void)out_size;

    const int nchunks = (NNODES + 1023) / 1024;  // 98

    // zero deg (400 KB) + bucket_fill (contiguous after deg's 256B pad)
    hipMemsetAsync(deg, 0, ((size_t)NNODES * 4 + 255 + (size_t)NB * 4 + 255) & ~(size_t)255,
                   stream);

    // in-degree counts
    count_kernel<<<NEDGES / 256, 256, 0, stream>>>(dst, deg, NEDGES);

    // CSR row offsets (exclusive scan)
    scan1_kernel<<<nchunks, 256, 0, stream>>>(deg, row_off, partial, NNODES);
    scan2_kernel<<<1, 128, 0, stream>>>(partial, row_off, nchunks, NNODES);
    scan3_kernel<<<(NNODES + 255) / 256, 256, 0, stream>>>(row_off, partial, NNODES);

    // CSR adjacency fill: binned two-pass scatter; pass 2 fuses dedup + norm
    fill1_kernel<<<(NEDGES + TILE - 1) / TILE, 256, 0, stream>>>(src, dst, row_off,
                                                                 bucket_fill, staging, NEDGES);
    fill2_kernel<<<NB, 256, 0, stream>>>(row_off, staging, csr_src, nrm, NNODES);

    // layer 1: lin -> aggregate -> combine + relu
    lin_kernel<INC><<<(NNODES + 63) / 64, 256, 0, stream>>>(x, w1_lin, b1_lin, bufA, NNODES);
    agg_h_kernel<<<NNODES / 4, 256, 0, stream>>>(bufA, row_off, csr_src, nrm, w1_pan, bufB,
                                                 NNODES);

    // layer 2: lin -> aggregate fused with edge-head projection
    lin_kernel<HIDC><<<(NNODES + 63) / 64, 256, 0, stream>>>(bufB, w2_lin, b2_lin, bufA, NNODES);
    agg_pq_kernel<<<NNODES / 4, 256, 0, stream>>>(bufA, row_off, csr_src, nrm, w2_pan, wc,
                                                  pq, NNODES);

    // edge head: out[e] = p[src[e]] + q[dst[e]] + bc
    edge_out_kernel<<<NEDGES / 256, 256, 0, stream>>>(src, dst, pq, bc, out, NEDGES);
}

// Round 7
// 373.605 us; speedup vs baseline: 2.5954x; 1.1786x over previous
//
#include <hip/hip_runtime.h>

#define NNODES 100000
#define NEDGES 1600000
#define INC 128
#define HIDC 64
#define BSHIFT 9                      // 512 nodes per bucket
#define NB ((NNODES + 511) / 512)     // 196 buckets
#define TILE 8192                     // edges per fill1 workgroup (32/thread)
#define HSLOTS 16384                  // LDS hash slots in fill2 (64 KB)

// Per edge: in-degree count (for CSR).
__global__ void count_kernel(const int* __restrict__ dst, int* __restrict__ deg, int n_edges) {
    int e = blockIdx.x * blockDim.x + threadIdx.x;
    if (e >= n_edges) return;
    atomicAdd(&deg[dst[e]], 1);
}

// Exclusive scan of deg -> row_off, 1024-element chunks.
__global__ void scan1_kernel(const int* __restrict__ deg, int* __restrict__ row_off,
                             int* __restrict__ partial, int n) {
    __shared__ int sdata[256];
    int t = threadIdx.x;
    int base = blockIdx.x * 1024 + t * 4;
    int v0 = (base + 0 < n) ? deg[base + 0] : 0;
    int v1 = (base + 1 < n) ? deg[base + 1] : 0;
    int v2 = (base + 2 < n) ? deg[base + 2] : 0;
    int v3 = (base + 3 < n) ? deg[base + 3] : 0;
    int sum = v0 + v1 + v2 + v3;
    sdata[t] = sum;
    __syncthreads();
    for (int off = 1; off < 256; off <<= 1) {
        int x = (t >= off) ? sdata[t - off] : 0;
        __syncthreads();
        sdata[t] += x;
        __syncthreads();
    }
    int excl = sdata[t] - sum;
    if (base + 0 < n) row_off[base + 0] = excl;
    if (base + 1 < n) row_off[base + 1] = excl + v0;
    if (base + 2 < n) row_off[base + 2] = excl + v0 + v1;
    if (base + 3 < n) row_off[base + 3] = excl + v0 + v1 + v2;
    if (t == 255) partial[blockIdx.x] = sdata[255];
}

// Scan the 98 chunk totals in parallel (one 128-thread block).
__global__ void scan2_kernel(int* __restrict__ partial, int* __restrict__ row_off,
                             int nchunks, int n) {
    __shared__ int sdata[128];
    int t = threadIdx.x;
    int v = (t < nchunks) ? partial[t] : 0;
    sdata[t] = v;
    __syncthreads();
    for (int off = 1; off < 128; off <<= 1) {
        int x = (t >= off) ? sdata[t - off] : 0;
        __syncthreads();
        sdata[t] += x;
        __syncthreads();
    }
    if (t < nchunks) partial[t] = sdata[t] - v;  // exclusive chunk offset
    if (t == 127) row_off[n] = sdata[127];       // grand total
}

__global__ void scan3_kernel(int* __restrict__ row_off, const int* __restrict__ partial, int n) {
    int i = blockIdx.x * blockDim.x + threadIdx.x;
    if (i >= n) return;
    row_off[i] += partial[i >> 10];
}

// fill pass 1: bin edges into bucket-contiguous staging chunks.
// staged word = (dst & 511) << 17 | src   (src < 2^17, dlocal < 2^9)
__global__ void fill1_kernel(const int* __restrict__ src, const int* __restrict__ dst,
                             const int* __restrict__ row_off, int* __restrict__ bucket_fill,
                             unsigned int* __restrict__ staging, int n_edges) {
    __shared__ int cnt[NB];
    __shared__ int basepos[NB];
    int t = threadIdx.x;
    for (int i = t; i < NB; i += 256) cnt[i] = 0;
    __syncthreads();
    int tile0 = blockIdx.x * TILE;
    unsigned int sv[32];
    int meta[32];
#pragma unroll
    for (int i = 0; i < 32; i++) {
        int e = tile0 + i * 256 + t;
        meta[i] = -1;
        sv[i] = 0;
        if (e < n_edges) {
            int s = src[e], d = dst[e];
            int b = d >> BSHIFT;
            int r = atomicAdd(&cnt[b], 1);      // rank within (tile, bucket); < TILE
            meta[i] = (b << 13) | r;
            sv[i] = ((unsigned)(d & 511) << 17) | (unsigned)s;
        }
    }
    __syncthreads();
    for (int i = t; i < NB; i += 256) {
        int c = cnt[i];
        int g = (c > 0) ? atomicAdd(&bucket_fill[i], c) : 0;
        basepos[i] = row_off[i << BSHIFT] + g;  // bucket's staging base == row_off at bucket start
    }
    __syncthreads();
#pragma unroll
    for (int i = 0; i < 32; i++) {
        if (meta[i] >= 0) {
            int b = meta[i] >> 13, r = meta[i] & 8191;
            staging[basepos[b] + r] = sv[i];
        }
    }
}

// fill pass 2: one WG per bucket; rank via LDS counters; writes stay in the
// bucket's contiguous csr region. Fused: per-(node,src) dedup via LDS hash ->
// distinct-incoming count -> norm = 1/(1+distinct).
__global__ void fill2_kernel(const int* __restrict__ row_off,
                             const unsigned int* __restrict__ staging,
                             int* __restrict__ csr_src, float* __restrict__ norm,
                             int n_nodes) {
    __shared__ int cnt[512];
    __shared__ int dcount[512];
    __shared__ int off[513];
    __shared__ unsigned int ht[HSLOTS];
    int t = threadIdx.x;
    int node0 = blockIdx.x << BSHIFT;
    int nn = min(512, n_nodes - node0);
    for (int i = t; i < 512; i += 256) { cnt[i] = 0; dcount[i] = 0; }
    for (int i = t; i <= nn; i += 256) off[i] = row_off[node0 + i];
    {   // vectorized sentinel init
        uint4* h4 = (uint4*)ht;
        uint4 ff = make_uint4(0xFFFFFFFFu, 0xFFFFFFFFu, 0xFFFFFFFFu, 0xFFFFFFFFu);
        for (int i = t; i < HSLOTS / 4; i += 256) h4[i] = ff;
    }
    __syncthreads();
    int base = off[0], end = off[nn];
    for (int i = base + t; i < end; i += 256) {
        unsigned int w = staging[i];
        int s = (int)(w & 0x1FFFFu);
        int dl = (int)(w >> 17);
        int r = atomicAdd(&cnt[dl], 1);
        csr_src[off[dl] + r] = s;
        if (s != node0 + dl) {  // self-loops merge with the I-diagonal
            unsigned int slot = ((w * 2654435761u) >> 12) & (HSLOTS - 1);
            while (true) {
                unsigned int prev = atomicCAS(&ht[slot], 0xFFFFFFFFu, w);
                if (prev == 0xFFFFFFFFu) { atomicAdd(&dcount[dl], 1); break; }
                if (prev == w) break;
                slot = (slot + 1) & (HSLOTS - 1);
            }
        }
    }
    __syncthreads();
    for (int i = t; i < nn; i += 256)
        norm[node0 + i] = 1.0f / (1.0f + (float)dcount[i]);
}

// W44[k][j] = sum_i w2_lin[k][i] * W4[i][j];  bias4[j] = sum_i b2[i] * W4[i][j]
// W4[i][j] = j<2 ? wc[i*2+j] : wc[(64+i)*2 + (j-2)]   (p-half | q-half of wc)
__global__ void wc44_kernel(const float* __restrict__ w2_lin, const float* __restrict__ b2,
                            const float* __restrict__ wc, float* __restrict__ w44,
                            float* __restrict__ bias4) {
    int t = threadIdx.x;
    int k = t >> 2, j = t & 3;
    float acc = 0.0f;
#pragma unroll 8
    for (int i = 0; i < 64; i++) {
        float w4 = (j < 2) ? wc[i * 2 + j] : wc[(64 + i) * 2 + (j - 2)];
        acc += w2_lin[k * 64 + i] * w4;
    }
    w44[k * 4 + j] = acc;
    if (k == 0) {
        float b = 0.0f;
        for (int i = 0; i < 64; i++) {
            float w4 = (j < 2) ? wc[i * 2 + j] : wc[(64 + i) * 2 + (j - 2)];
            b += b2[i] * w4;
        }
        bias4[j] = b;
    }
}

// Register-tiled GEMM: out[64-node tile, 64 ch] = x @ w + b.
template <int K>
__global__ __launch_bounds__(256) void lin_kernel(const float* __restrict__ x,
                                                  const float* __restrict__ w,
                                                  const float* __restrict__ b,
                                                  float* __restrict__ out, int n_nodes) {
    __shared__ float xs[64][K + 4];
    int t = threadIdx.x;
    int node0 = blockIdx.x * 64;
    int nn = min(64, n_nodes - node0);
    constexpr int C4 = K / 4;
    for (int idx = t; idx < 64 * C4; idx += 256) {
        int row = idx / C4, c4 = idx % C4;
        float4 v = make_float4(0.f, 0.f, 0.f, 0.f);
        if (row < nn) v = *(const float4*)(x + (size_t)(node0 + row) * K + c4 * 4);
        *(float4*)(&xs[row][c4 * 4]) = v;
    }
    __syncthreads();
    int tn = t >> 4, tc = t & 15;
    int n0 = tn * 4, c0 = tc * 4;
    float4 bb = *(const float4*)(b + c0);
    float acc[4][4];
#pragma unroll
    for (int i = 0; i < 4; i++) {
        acc[i][0] = bb.x; acc[i][1] = bb.y; acc[i][2] = bb.z; acc[i][3] = bb.w;
    }
#pragma unroll 4
    for (int k = 0; k < K; k += 4) {
        float xr[4][4], wr[4][4];
#pragma unroll
        for (int i = 0; i < 4; i++)
            *(float4*)&xr[i][0] = *(const float4*)(&xs[n0 + i][k]);
#pragma unroll
        for (int j = 0; j < 4; j++)
            *(float4*)&wr[j][0] = *(const float4*)(w + (size_t)(k + j) * 64 + c0);
#pragma unroll
        for (int i = 0; i < 4; i++)
#pragma unroll
            for (int kk = 0; kk < 4; kk++)
#pragma unroll
                for (int j = 0; j < 4; j++)
                    acc[i][j] += xr[i][kk] * wr[kk][j];
    }
#pragma unroll
    for (int i = 0; i < 4; i++) {
        int node = node0 + n0 + i;
        if (node < n_nodes) {
            float4 v = make_float4(acc[i][0], acc[i][1], acc[i][2], acc[i][3]);
            *(float4*)(out + (size_t)node * 64 + c0) = v;
        }
    }
}

// 8-wide-unrolled CSR gather-sum for one node (lane = channel).
__device__ __forceinline__ float gather_row_sum(const float* __restrict__ lin,
                                                const int* __restrict__ csr_src,
                                                int e0, int e1, int c) {
    float acc = 0.0f;
    int e = e0;
    for (; e + 8 <= e1; e += 8) {
        int s0 = csr_src[e + 0], s1 = csr_src[e + 1];
        int s2 = csr_src[e + 2], s3 = csr_src[e + 3];
        int s4 = csr_src[e + 4], s5 = csr_src[e + 5];
        int s6 = csr_src[e + 6], s7 = csr_src[e + 7];
        float v0 = lin[s0 * 64 + c], v1 = lin[s1 * 64 + c];
        float v2 = lin[s2 * 64 + c], v3 = lin[s3 * 64 + c];
        float v4 = lin[s4 * 64 + c], v5 = lin[s5 * 64 + c];
        float v6 = lin[s6 * 64 + c], v7 = lin[s7 * 64 + c];
        acc += ((v0 + v1) + (v2 + v3)) + ((v4 + v5) + (v6 + v7));
    }
    if (e + 4 <= e1) {
        int s0 = csr_src[e + 0], s1 = csr_src[e + 1];
        int s2 = csr_src[e + 2], s3 = csr_src[e + 3];
        float v0 = lin[s0 * 64 + c], v1 = lin[s1 * 64 + c];
        float v2 = lin[s2 * 64 + c], v3 = lin[s3 * 64 + c];
        acc += (v0 + v1) + (v2 + v3);
        e += 4;
    }
    for (; e < e1; e++) acc += lin[csr_src[e] * 64 + c];
    return acc;
}

// One wave per node: CSR gather-sum + PAN combine + relu (layer 1) fused with
// the rank-4 layer-2 projection: u[node][j] = h1[node] @ w44[:,j] + bias4[j].
__global__ void agg_h_kernel(const float* __restrict__ lin, const int* __restrict__ row_off,
                             const int* __restrict__ csr_src, const float* __restrict__ norm,
                             const float* __restrict__ wpan, const float* __restrict__ w44,
                             const float* __restrict__ bias4, float* __restrict__ out,
                             float* __restrict__ u, int n_nodes) {
    int t = threadIdx.x;
    int node = blockIdx.x * 4 + (t >> 6);
    int c = t & 63;
    if (node >= n_nodes) return;
    int e0 = row_off[node], e1 = row_off[node + 1];
    float acc = gather_row_sum(lin, csr_src, e0, e1, c);
    float w0 = wpan[0];
    float w01 = wpan[0] * wpan[1];
    float v = norm[node] * (w0 * lin[node * 64 + c] + w01 * acc);
    v = fmaxf(v, 0.0f);                      // h1[node, c]
    out[node * 64 + c] = v;
    float4 wv = *(const float4*)(w44 + c * 4);
    float a0 = v * wv.x, a1 = v * wv.y, a2 = v * wv.z, a3 = v * wv.w;
    for (int off = 32; off; off >>= 1) {
        a0 += __shfl_xor(a0, off);
        a1 += __shfl_xor(a1, off);
        a2 += __shfl_xor(a2, off);
        a3 += __shfl_xor(a3, off);
    }
    if (c == 0) {
        float4 bb = *(const float4*)bias4;
        *(float4*)(u + node * 4) =
            make_float4(a0 + bb.x, a1 + bb.y, a2 + bb.z, a3 + bb.w);
    }
}

// Layer-2 aggregate on the rank-4 table: pq[n,j] = norm*(w0*u[n,j] + w01*sum u[src,j]).
__global__ void agg_pq4_kernel(const float* __restrict__ u, const int* __restrict__ row_off,
                               const int* __restrict__ csr_src, const float* __restrict__ norm,
                               const float* __restrict__ wpan, float* __restrict__ pq,
                               int n_nodes) {
    int t = threadIdx.x;
    int node = blockIdx.x * 64 + (t >> 2);
    int j = t & 3;
    if (node >= n_nodes) return;
    int e0 = row_off[node], e1 = row_off[node + 1];
    float acc = 0.0f;
    int e = e0;
    for (; e + 4 <= e1; e += 4) {
        int s0 = csr_src[e + 0], s1 = csr_src[e + 1];
        int s2 = csr_src[e + 2], s3 = csr_src[e + 3];
        float v0 = u[s0 * 4 + j], v1 = u[s1 * 4 + j];
        float v2 = u[s2 * 4 + j], v3 = u[s3 * 4 + j];
        acc += (v0 + v1) + (v2 + v3);
    }
    for (; e < e1; e++) acc += u[csr_src[e] * 4 + j];
    float w0 = wpan[0];
    float w01 = wpan[0] * wpan[1];
    pq[node * 4 + j] = norm[node] * (w0 * u[node * 4 + j] + w01 * acc);
}

__global__ void edge_out_kernel(const int* __restrict__ src, const int* __restrict__ dst,
                                const float* __restrict__ pq, const float* __restrict__ bc,
                                float* __restrict__ out, int n_edges) {
    int e = blockIdx.x * blockDim.x + threadIdx.x;
    if (e >= n_edges) return;
    int r = src[e], c = dst[e];
    float2 p = *(const float2*)(pq + r * 4);
    float2 q = *(const float2*)(pq + c * 4 + 2);
    float2 o = make_float2(p.x + q.x + bc[0], p.y + q.y + bc[1]);
    *(float2*)(out + e * 2) = o;
}

extern "C" void kernel_launch(void* const* d_in, const int* in_sizes, int n_in,
                              void* d_out, int out_size, void* d_ws, size_t ws_size,
                              hipStream_t stream) {
    const float* x      = (const float*)d_in[0];
    const int*   eidx   = (const int*)d_in[1];
    const float* w1_lin = (const float*)d_in[2];
    const float* b1_lin = (const float*)d_in[3];
    const float* w1_pan = (const float*)d_in[4];
    const float* w2_lin = (const float*)d_in[5];
    const float* b2_lin = (const float*)d_in[6];
    const float* w2_pan = (const float*)d_in[7];
    const float* wc     = (const float*)d_in[8];
    const float* bc     = (const float*)d_in[9];
    float* out = (float*)d_out;

    const int* src = eidx;           // edge_index[0]
    const int* dst = eidx + NEDGES;  // edge_index[1]

    // ---- workspace carve-up (all 256B-aligned) ----
    char* ws = (char*)d_ws;
    size_t off = 0;
    auto carve = [&](size_t bytes) {
        char* p = ws + off;
        off = (off + bytes + 255) & ~(size_t)255;
        return p;
    };
    int*   deg      = (int*)carve((size_t)NNODES * 4);
    int*   bucket_fill = (int*)carve((size_t)NB * 4);
    int*   row_off  = (int*)carve((size_t)(NNODES + 1) * 4);
    int*   partial  = (int*)carve((size_t)128 * 4);
    unsigned int* staging = (unsigned int*)carve((size_t)NEDGES * 4);
    int*   csr_src  = (int*)carve((size_t)NEDGES * 4);
    float* nrm      = (float*)carve((size_t)NNODES * 4);
    float* bufA     = (float*)carve((size_t)NNODES * HIDC * 4);  // lin1 (25.6 MB)
    float* bufB     = (float*)carve((size_t)NNODES * HIDC * 4);  // h1 (25.6 MB)
    float* u        = (float*)carve((size_t)NNODES * 4 * 4);     // rank-4 table
    float* pq       = (float*)carve((size_t)NNODES * 4 * 4);
    float* w44      = (float*)carve((size_t)64 * 4 * 4);
    float* bias4    = (float*)carve((size_t)4 * 4);
    (void)ws_size; (void)in_sizes; (void)n_in; (void)out_size;

    const int nchunks = (NNODES + 1023) / 1024;  // 98

    hipMemsetAsync(deg, 0, ((size_t)NNODES * 4 + 255 + (size_t)NB * 4 + 255) & ~(size_t)255,
                   stream);

    // in-degree counts
    count_kernel<<<NEDGES / 256, 256, 0, stream>>>(dst, deg, NEDGES);

    // CSR row offsets (exclusive scan)
    scan1_kernel<<<nchunks, 256, 0, stream>>>(deg, row_off, partial, NNODES);
    scan2_kernel<<<1, 128, 0, stream>>>(partial, row_off, nchunks, NNODES);
    scan3_kernel<<<(NNODES + 255) / 256, 256, 0, stream>>>(row_off, partial, NNODES);

    // CSR adjacency fill: binned two-pass scatter; pass 2 fuses dedup + norm
    fill1_kernel<<<(NEDGES + TILE - 1) / TILE, 256, 0, stream>>>(src, dst, row_off,
                                                                 bucket_fill, staging, NEDGES);
    fill2_kernel<<<NB, 256, 0, stream>>>(row_off, staging, csr_src, nrm, NNODES);

    // composite rank-4 weights for layer2+head: w44 = w2_lin @ [wc_p|wc_q]
    wc44_kernel<<<1, 256, 0, stream>>>(w2_lin, b2_lin, wc, w44, bias4);

    // layer 1: lin -> aggregate+relu fused with rank-4 projection -> u
    lin_kernel<INC><<<(NNODES + 63) / 64, 256, 0, stream>>>(x, w1_lin, b1_lin, bufA, NNODES);
    agg_h_kernel<<<(NNODES + 3) / 4, 256, 0, stream>>>(bufA, row_off, csr_src, nrm, w1_pan,
                                                       w44, bias4, bufB, u, NNODES);

    // layer 2 aggregate on the rank-4 table
    agg_pq4_kernel<<<(NNODES + 63) / 64, 256, 0, stream>>>(u, row_off, csr_src, nrm, w2_pan,
                                                           pq, NNODES);

    // edge head: out[e] = p[src[e]] + q[dst[e]] + bc
    edge_out_kernel<<<NEDGES / 256, 256, 0, stream>>>(src, dst, pq, bc, out, NEDGES);
}

// Round 8
// 300.837 us; speedup vs baseline: 3.2231x; 1.2419x over previous
//
#include <hip/hip_runtime.h>

#define NNODES 100000
#define NEDGES 1600000
#define INC 128
#define HIDC 64
#define BSHIFT 9                      // 512 nodes per bucket
#define NB ((NNODES + 511) / 512)     // 196 buckets
#define TILE 8192                     // edges per fill1 workgroup (32/thread)
#define HSLOTS 16384                  // LDS hash slots in fill2 (64 KB)
#define CAP 16384                     // staging words per bucket (avg load 8163)

// fill pass 1: bin edges into fixed-capacity per-bucket staging regions.
// staged word = (dst & 511) << 17 | src   (src < 2^17, dlocal < 2^9)
__global__ void fill1_kernel(const int* __restrict__ src, const int* __restrict__ dst,
                             int* __restrict__ bucket_fill,
                             unsigned int* __restrict__ staging, int n_edges) {
    __shared__ int cnt[NB];
    __shared__ int basepos[NB];
    int t = threadIdx.x;
    for (int i = t; i < NB; i += 256) cnt[i] = 0;
    __syncthreads();
    int tile0 = blockIdx.x * TILE;
    unsigned int sv[32];
    int meta[32];
#pragma unroll
    for (int i = 0; i < 32; i++) {
        int e = tile0 + i * 256 + t;
        meta[i] = -1;
        sv[i] = 0;
        if (e < n_edges) {
            int s = src[e], d = dst[e];
            int b = d >> BSHIFT;
            int r = atomicAdd(&cnt[b], 1);      // rank within (tile, bucket); < TILE
            meta[i] = (b << 13) | r;
            sv[i] = ((unsigned)(d & 511) << 17) | (unsigned)s;
        }
    }
    __syncthreads();
    for (int i = t; i < NB; i += 256) {
        int c = cnt[i];
        int g = (c > 0) ? atomicAdd(&bucket_fill[i], c) : 0;
        basepos[i] = (i << 14) + g;             // bucket region = [i*CAP, (i+1)*CAP)
    }
    __syncthreads();
#pragma unroll
    for (int i = 0; i < 32; i++) {
        if (meta[i] >= 0) {
            int b = meta[i] >> 13, r = meta[i] & 8191;
            staging[basepos[b] + r] = sv[i];
        }
    }
}

// fill pass 2: one WG per bucket. Phase A streams the bucket's staged edges:
// per-node counts (rank recorded in LDS), per-(node,src) dedup via LDS hash.
// Then: bucket base from an in-block scan of bucket totals, per-node prefix
// -> row_off written directly; norm = 1/(1+distinct). Phase B scatters csr
// (L2-hot re-read, ranks from LDS, single-WG-owned contiguous writes).
__global__ __launch_bounds__(256) void fill2_kernel(
        const int* __restrict__ bucket_fill, const unsigned int* __restrict__ staging,
        int* __restrict__ csr_src, int* __restrict__ row_off,
        float* __restrict__ norm, int n_nodes) {
    __shared__ int cnt[512];
    __shared__ int off[513];
    __shared__ int bscan[256];
    __shared__ int pscan[256];
    __shared__ int dcount[512];
    __shared__ unsigned short rank16[CAP];   // 32 KB
    __shared__ unsigned int ht[HSLOTS];      // 64 KB
    __shared__ int s_base, s_total;
    int t = threadIdx.x;
    int b = blockIdx.x;
    int node0 = b << BSHIFT;
    int nn = min(512, n_nodes - node0);
    int v = (t < NB) ? bucket_fill[t] : 0;
    bscan[t] = v;
    for (int i = t; i < 512; i += 256) { cnt[i] = 0; dcount[i] = 0; }
    {   // vectorized sentinel init
        uint4* h4 = (uint4*)ht;
        uint4 ff = make_uint4(0xFFFFFFFFu, 0xFFFFFFFFu, 0xFFFFFFFFu, 0xFFFFFFFFu);
        for (int i = t; i < HSLOTS / 4; i += 256) h4[i] = ff;
    }
    __syncthreads();
    for (int o = 1; o < 256; o <<= 1) {       // inclusive scan of bucket totals
        int xx = (t >= o) ? bscan[t - o] : 0;
        __syncthreads();
        bscan[t] += xx;
        __syncthreads();
    }
    if (t == b) { s_total = v; s_base = bscan[b] - v; }   // b < 196 <= 255
    __syncthreads();
    int start = b << 14;                      // b*CAP
    int total = s_total;
    // phase A: count + rank + dedup
    for (int li = t; li < total; li += 256) {
        unsigned int w = staging[start + li];
        int s = (int)(w & 0x1FFFFu);
        int dl = (int)(w >> 17);
        int r = atomicAdd(&cnt[dl], 1);
        rank16[li] = (unsigned short)r;
        if (s != node0 + dl) {  // self-loops merge with the I-diagonal
            unsigned int slot = ((w * 2654435761u) >> 12) & (HSLOTS - 1);
            while (true) {
                unsigned int prev = atomicCAS(&ht[slot], 0xFFFFFFFFu, w);
                if (prev == 0xFFFFFFFFu) { atomicAdd(&dcount[dl], 1); break; }
                if (prev == w) break;
                slot = (slot + 1) & (HSLOTS - 1);
            }
        }
    }
    __syncthreads();
    // exclusive prefix of cnt[0..511] -> off (global row offsets)
    int c0 = cnt[2 * t], c1 = cnt[2 * t + 1];
    pscan[t] = c0 + c1;
    __syncthreads();
    for (int o = 1; o < 256; o <<= 1) {
        int xx = (t >= o) ? pscan[t - o] : 0;
        __syncthreads();
        pscan[t] += xx;
        __syncthreads();
    }
    int pe = pscan[t] - (c0 + c1);
    off[2 * t]     = s_base + pe;
    off[2 * t + 1] = s_base + pe + c0;
    if (t == 255) off[512] = s_base + pscan[255];
    __syncthreads();
    // row_off + norm epilogue
    for (int i = t; i < nn; i += 256) {
        row_off[node0 + i] = off[i];
        norm[node0 + i] = 1.0f / (1.0f + (float)dcount[i]);
    }
    if (t == 0 && node0 + 512 >= n_nodes) row_off[n_nodes] = off[nn];
    // phase B: scatter csr (contiguous bucket region, full-line writebacks)
    for (int li = t; li < total; li += 256) {
        unsigned int w = staging[start + li];
        int s = (int)(w & 0x1FFFFu);
        int dl = (int)(w >> 17);
        csr_src[off[dl] + (int)rank16[li]] = s;
    }
}

// Register-tiled GEMM: out[64-node tile, 64 ch] = x @ w + b.
// Block 0 additionally computes the composite rank-4 weights:
//   w44 = w2_lin @ [wc_p|wc_q],  bias4 = b2 @ [wc_p|wc_q]
template <int K, bool DOWC>
__global__ __launch_bounds__(256) void lin_kernel(const float* __restrict__ x,
                                                  const float* __restrict__ w,
                                                  const float* __restrict__ b,
                                                  float* __restrict__ out, int n_nodes,
                                                  const float* __restrict__ w2_lin,
                                                  const float* __restrict__ b2,
                                                  const float* __restrict__ wc,
                                                  float* __restrict__ w44,
                                                  float* __restrict__ bias4) {
    __shared__ float xs[64][K + 4];
    int t = threadIdx.x;
    int node0 = blockIdx.x * 64;
    int nn = min(64, n_nodes - node0);
    constexpr int C4 = K / 4;
    for (int idx = t; idx < 64 * C4; idx += 256) {
        int row = idx / C4, c4 = idx % C4;
        float4 v = make_float4(0.f, 0.f, 0.f, 0.f);
        if (row < nn) v = *(const float4*)(x + (size_t)(node0 + row) * K + c4 * 4);
        *(float4*)(&xs[row][c4 * 4]) = v;
    }
    __syncthreads();
    int tn = t >> 4, tc = t & 15;
    int n0 = tn * 4, c0 = tc * 4;
    float4 bb = *(const float4*)(b + c0);
    float acc[4][4];
#pragma unroll
    for (int i = 0; i < 4; i++) {
        acc[i][0] = bb.x; acc[i][1] = bb.y; acc[i][2] = bb.z; acc[i][3] = bb.w;
    }
#pragma unroll 4
    for (int k = 0; k < K; k += 4) {
        float xr[4][4], wr[4][4];
#pragma unroll
        for (int i = 0; i < 4; i++)
            *(float4*)&xr[i][0] = *(const float4*)(&xs[n0 + i][k]);
#pragma unroll
        for (int j = 0; j < 4; j++)
            *(float4*)&wr[j][0] = *(const float4*)(w + (size_t)(k + j) * 64 + c0);
#pragma unroll
        for (int i = 0; i < 4; i++)
#pragma unroll
            for (int kk = 0; kk < 4; kk++)
#pragma unroll
                for (int j = 0; j < 4; j++)
                    acc[i][j] += xr[i][kk] * wr[kk][j];
    }
#pragma unroll
    for (int i = 0; i < 4; i++) {
        int node = node0 + n0 + i;
        if (node < n_nodes) {
            float4 v = make_float4(acc[i][0], acc[i][1], acc[i][2], acc[i][3]);
            *(float4*)(out + (size_t)node * 64 + c0) = v;
        }
    }
    if (DOWC && blockIdx.x == 0) {
        int k = t >> 2, j = t & 3;
        float a = 0.0f;
#pragma unroll 8
        for (int i = 0; i < 64; i++) {
            float w4 = (j < 2) ? wc[i * 2 + j] : wc[(64 + i) * 2 + (j - 2)];
            a += w2_lin[k * 64 + i] * w4;
        }
        w44[k * 4 + j] = a;
        if (k == 0) {
            float bb4 = 0.0f;
            for (int i = 0; i < 64; i++) {
                float w4 = (j < 2) ? wc[i * 2 + j] : wc[(64 + i) * 2 + (j - 2)];
                bb4 += b2[i] * w4;
            }
            bias4[j] = bb4;
        }
    }
}

// 8-wide-unrolled CSR gather-sum for one node (lane = channel).
__device__ __forceinline__ float gather_row_sum(const float* __restrict__ lin,
                                                const int* __restrict__ csr_src,
                                                int e0, int e1, int c) {
    float acc = 0.0f;
    int e = e0;
    for (; e + 8 <= e1; e += 8) {
        int s0 = csr_src[e + 0], s1 = csr_src[e + 1];
        int s2 = csr_src[e + 2], s3 = csr_src[e + 3];
        int s4 = csr_src[e + 4], s5 = csr_src[e + 5];
        int s6 = csr_src[e + 6], s7 = csr_src[e + 7];
        float v0 = lin[s0 * 64 + c], v1 = lin[s1 * 64 + c];
        float v2 = lin[s2 * 64 + c], v3 = lin[s3 * 64 + c];
        float v4 = lin[s4 * 64 + c], v5 = lin[s5 * 64 + c];
        float v6 = lin[s6 * 64 + c], v7 = lin[s7 * 64 + c];
        acc += ((v0 + v1) + (v2 + v3)) + ((v4 + v5) + (v6 + v7));
    }
    if (e + 4 <= e1) {
        int s0 = csr_src[e + 0], s1 = csr_src[e + 1];
        int s2 = csr_src[e + 2], s3 = csr_src[e + 3];
        float v0 = lin[s0 * 64 + c], v1 = lin[s1 * 64 + c];
        float v2 = lin[s2 * 64 + c], v3 = lin[s3 * 64 + c];
        acc += (v0 + v1) + (v2 + v3);
        e += 4;
    }
    for (; e < e1; e++) acc += lin[csr_src[e] * 64 + c];
    return acc;
}

// One wave per node: CSR gather-sum + PAN combine + relu (layer 1) fused with
// the rank-4 layer-2 projection: u[node][j] = h1[node] @ w44[:,j] + bias4[j].
// h1 itself is never materialized to global memory.
__global__ void agg_h_kernel(const float* __restrict__ lin, const int* __restrict__ row_off,
                             const int* __restrict__ csr_src, const float* __restrict__ norm,
                             const float* __restrict__ wpan, const float* __restrict__ w44,
                             const float* __restrict__ bias4, float* __restrict__ u,
                             int n_nodes) {
    int t = threadIdx.x;
    int node = blockIdx.x * 4 + (t >> 6);
    int c = t & 63;
    if (node >= n_nodes) return;
    int e0 = row_off[node], e1 = row_off[node + 1];
    float acc = gather_row_sum(lin, csr_src, e0, e1, c);
    float w0 = wpan[0];
    float w01 = wpan[0] * wpan[1];
    float v = norm[node] * (w0 * lin[node * 64 + c] + w01 * acc);
    v = fmaxf(v, 0.0f);                      // h1[node, c]
    float4 wv = *(const float4*)(w44 + c * 4);
    float a0 = v * wv.x, a1 = v * wv.y, a2 = v * wv.z, a3 = v * wv.w;
    for (int off = 32; off; off >>= 1) {
        a0 += __shfl_xor(a0, off);
        a1 += __shfl_xor(a1, off);
        a2 += __shfl_xor(a2, off);
        a3 += __shfl_xor(a3, off);
    }
    if (c == 0) {
        float4 bb = *(const float4*)bias4;
        *(float4*)(u + node * 4) =
            make_float4(a0 + bb.x, a1 + bb.y, a2 + bb.z, a3 + bb.w);
    }
}

// Layer-2 aggregate on the rank-4 table: pq[n,j] = norm*(w0*u[n,j] + w01*sum u[src,j]).
__global__ void agg_pq4_kernel(const float* __restrict__ u, const int* __restrict__ row_off,
                               const int* __restrict__ csr_src, const float* __restrict__ norm,
                               const float* __restrict__ wpan, float* __restrict__ pq,
                               int n_nodes) {
    int t = threadIdx.x;
    int node = blockIdx.x * 64 + (t >> 2);
    int j = t & 3;
    if (node >= n_nodes) return;
    int e0 = row_off[node], e1 = row_off[node + 1];
    float acc = 0.0f;
    int e = e0;
    for (; e + 4 <= e1; e += 4) {
        int s0 = csr_src[e + 0], s1 = csr_src[e + 1];
        int s2 = csr_src[e + 2], s3 = csr_src[e + 3];
        float v0 = u[s0 * 4 + j], v1 = u[s1 * 4 + j];
        float v2 = u[s2 * 4 + j], v3 = u[s3 * 4 + j];
        acc += (v0 + v1) + (v2 + v3);
    }
    for (; e < e1; e++) acc += u[csr_src[e] * 4 + j];
    float w0 = wpan[0];
    float w01 = wpan[0] * wpan[1];
    pq[node * 4 + j] = norm[node] * (w0 * u[node * 4 + j] + w01 * acc);
}

__global__ void edge_out_kernel(const int* __restrict__ src, const int* __restrict__ dst,
                                const float* __restrict__ pq, const float* __restrict__ bc,
                                float* __restrict__ out, int n_edges) {
    int e = blockIdx.x * blockDim.x + threadIdx.x;
    if (e >= n_edges) return;
    int r = src[e], c = dst[e];
    float2 p = *(const float2*)(pq + r * 4);
    float2 q = *(const float2*)(pq + c * 4 + 2);
    float2 o = make_float2(p.x + q.x + bc[0], p.y + q.y + bc[1]);
    *(float2*)(out + e * 2) = o;
}

extern "C" void kernel_launch(void* const* d_in, const int* in_sizes, int n_in,
                              void* d_out, int out_size, void* d_ws, size_t ws_size,
                              hipStream_t stream) {
    const float* x      = (const float*)d_in[0];
    const int*   eidx   = (const int*)d_in[1];
    const float* w1_lin = (const float*)d_in[2];
    const float* b1_lin = (const float*)d_in[3];
    const float* w1_pan = (const float*)d_in[4];
    const float* w2_lin = (const float*)d_in[5];
    const float* b2_lin = (const float*)d_in[6];
    const float* w2_pan = (const float*)d_in[7];
    const float* wc     = (const float*)d_in[8];
    const float* bc     = (const float*)d_in[9];
    float* out = (float*)d_out;

    const int* src = eidx;           // edge_index[0]
    const int* dst = eidx + NEDGES;  // edge_index[1]

    // ---- workspace carve-up (all 256B-aligned) ----
    char* ws = (char*)d_ws;
    size_t off = 0;
    auto carve = [&](size_t bytes) {
        char* p = ws + off;
        off = (off + bytes + 255) & ~(size_t)255;
        return p;
    };
    int*   bucket_fill = (int*)carve((size_t)NB * 4);
    int*   row_off  = (int*)carve((size_t)(NNODES + 1) * 4);
    unsigned int* staging = (unsigned int*)carve((size_t)NB * CAP * 4);  // 12.8 MB
    int*   csr_src  = (int*)carve((size_t)NEDGES * 4);
    float* nrm      = (float*)carve((size_t)NNODES * 4);
    float* bufA     = (float*)carve((size_t)NNODES * HIDC * 4);  // lin1 (25.6 MB)
    float* u        = (float*)carve((size_t)NNODES * 4 * 4);     // rank-4 table
    float* pq       = (float*)carve((size_t)NNODES * 4 * 4);
    float* w44      = (float*)carve((size_t)64 * 4 * 4);
    float* bias4    = (float*)carve((size_t)4 * 4);
    (void)ws_size; (void)in_sizes; (void)n_in; (void)out_size;

    hipMemsetAsync(bucket_fill, 0, (size_t)NB * 4, stream);

    // CSR build: binned two-pass scatter; pass 2 computes row_off + dedup + norm
    fill1_kernel<<<(NEDGES + TILE - 1) / TILE, 256, 0, stream>>>(src, dst, bucket_fill,
                                                                 staging, NEDGES);
    fill2_kernel<<<NB, 256, 0, stream>>>(bucket_fill, staging, csr_src, row_off, nrm, NNODES);

    // layer 1 GEMM (+ composite rank-4 weights in block 0)
    lin_kernel<INC, true><<<(NNODES + 63) / 64, 256, 0, stream>>>(
        x, w1_lin, b1_lin, bufA, NNODES, w2_lin, b2_lin, wc, w44, bias4);

    // layer 1 aggregate+relu fused with rank-4 projection -> u
    agg_h_kernel<<<(NNODES + 3) / 4, 256, 0, stream>>>(bufA, row_off, csr_src, nrm, w1_pan,
                                                       w44, bias4, u, NNODES);

    // layer 2 aggregate on the rank-4 table
    agg_pq4_kernel<<<(NNODES + 63) / 64, 256, 0, stream>>>(u, row_off, csr_src, nrm, w2_pan,
                                                           pq, NNODES);

    // edge head: out[e] = p[src[e]] + q[dst[e]] + bc
    edge_out_kernel<<<NEDGES / 256, 256, 0, stream>>>(src, dst, pq, bc, out, NEDGES);
}

// Round 9
// 280.118 us; speedup vs baseline: 3.4615x; 1.0740x over previous
//
#include <hip/hip_runtime.h>
#include <hip/hip_bf16.h>

#define NNODES 100000
#define NEDGES 1600000
#define INC 128
#define HIDC 64
#define BSHIFT 9                      // 512 nodes per bucket
#define NB ((NNODES + 511) / 512)     // 196 buckets
#define TILE 8192                     // edges per fill1 workgroup (32/thread)
#define HSLOTS 16384                  // LDS hash slots in fill2 (64 KB)
#define CAP 16384                     // staging words per bucket (avg load 8163)
#define NBLK_LIN ((NNODES + 63) / 64) // 1563 lin blocks in the fat kernel

__device__ __forceinline__ float bf2f(unsigned short h) {
    return __uint_as_float((unsigned)h << 16);
}

// ---- fat kernel: lin1 GEMM (blocks [0, NBLK_LIN)) + fill1 binning (rest) ----
// lin: out[64-node tile, 64 ch] = x @ w1 + b1, written as bf16.
//      Block 0 also computes w44 = w2_lin @ [wc_p|wc_q], bias4 = b2 @ [wc_p|wc_q].
// fill1: bin edges into fixed-capacity per-bucket staging regions.
//        staged word = (dst & 511) << 17 | src
__global__ __launch_bounds__(256) void lin_fill1_kernel(
        const float* __restrict__ x, const float* __restrict__ w,
        const float* __restrict__ b, unsigned short* __restrict__ out,
        const float* __restrict__ w2_lin, const float* __restrict__ b2,
        const float* __restrict__ wc, float* __restrict__ w44,
        float* __restrict__ bias4,
        const int* __restrict__ src, const int* __restrict__ dst,
        int* __restrict__ bucket_fill, unsigned int* __restrict__ staging) {
    __shared__ float xs[64][INC + 4];   // 33.8 KB; fill1 aliases the front
    int t = threadIdx.x;
    if (blockIdx.x < NBLK_LIN) {
        // ---------------- lin branch ----------------
        int node0 = blockIdx.x * 64;
        int nn = min(64, NNODES - node0);
        constexpr int C4 = INC / 4;
        for (int idx = t; idx < 64 * C4; idx += 256) {
            int row = idx / C4, c4 = idx % C4;
            float4 v = make_float4(0.f, 0.f, 0.f, 0.f);
            if (row < nn) v = *(const float4*)(x + (size_t)(node0 + row) * INC + c4 * 4);
            *(float4*)(&xs[row][c4 * 4]) = v;
        }
        __syncthreads();
        int tn = t >> 4, tc = t & 15;
        int n0 = tn * 4, c0 = tc * 4;
        float4 bb = *(const float4*)(b + c0);
        float acc[4][4];
#pragma unroll
        for (int i = 0; i < 4; i++) {
            acc[i][0] = bb.x; acc[i][1] = bb.y; acc[i][2] = bb.z; acc[i][3] = bb.w;
        }
#pragma unroll 4
        for (int k = 0; k < INC; k += 4) {
            float xr[4][4], wr[4][4];
#pragma unroll
            for (int i = 0; i < 4; i++)
                *(float4*)&xr[i][0] = *(const float4*)(&xs[n0 + i][k]);
#pragma unroll
            for (int j = 0; j < 4; j++)
                *(float4*)&wr[j][0] = *(const float4*)(w + (size_t)(k + j) * 64 + c0);
#pragma unroll
            for (int i = 0; i < 4; i++)
#pragma unroll
                for (int kk = 0; kk < 4; kk++)
#pragma unroll
                    for (int j = 0; j < 4; j++)
                        acc[i][j] += xr[i][kk] * wr[kk][j];
        }
#pragma unroll
        for (int i = 0; i < 4; i++) {
            int node = node0 + n0 + i;
            if (node < NNODES) {
                __hip_bfloat16 h0 = __float2bfloat16(acc[i][0]);
                __hip_bfloat16 h1 = __float2bfloat16(acc[i][1]);
                __hip_bfloat16 h2 = __float2bfloat16(acc[i][2]);
                __hip_bfloat16 h3 = __float2bfloat16(acc[i][3]);
                ushort4 pk = make_ushort4(*(unsigned short*)&h0, *(unsigned short*)&h1,
                                          *(unsigned short*)&h2, *(unsigned short*)&h3);
                *(ushort4*)(out + (size_t)node * 64 + c0) = pk;
            }
        }
        if (blockIdx.x == 0) {
            int k = t >> 2, j = t & 3;
            float a = 0.0f;
#pragma unroll 8
            for (int i = 0; i < 64; i++) {
                float w4 = (j < 2) ? wc[i * 2 + j] : wc[(64 + i) * 2 + (j - 2)];
                a += w2_lin[k * 64 + i] * w4;
            }
            w44[k * 4 + j] = a;
            if (k == 0) {
                float bb4 = 0.0f;
                for (int i = 0; i < 64; i++) {
                    float w4 = (j < 2) ? wc[i * 2 + j] : wc[(64 + i) * 2 + (j - 2)];
                    bb4 += b2[i] * w4;
                }
                bias4[j] = bb4;
            }
        }
    } else {
        // ---------------- fill1 branch ----------------
        int* cnt = (int*)&xs[0][0];
        int* basepos = cnt + NB;
        for (int i = t; i < NB; i += 256) cnt[i] = 0;
        __syncthreads();
        int tile0 = (blockIdx.x - NBLK_LIN) * TILE;
        unsigned int sv[32];
        int meta[32];
#pragma unroll
        for (int i = 0; i < 32; i++) {
            int e = tile0 + i * 256 + t;
            meta[i] = -1;
            sv[i] = 0;
            if (e < NEDGES) {
                int s = src[e], d = dst[e];
                int bkt = d >> BSHIFT;
                int r = atomicAdd(&cnt[bkt], 1);
                meta[i] = (bkt << 13) | r;
                sv[i] = ((unsigned)(d & 511) << 17) | (unsigned)s;
            }
        }
        __syncthreads();
        for (int i = t; i < NB; i += 256) {
            int c = cnt[i];
            int g = (c > 0) ? atomicAdd(&bucket_fill[i], c) : 0;
            basepos[i] = (i << 14) + g;
        }
        __syncthreads();
#pragma unroll
        for (int i = 0; i < 32; i++) {
            if (meta[i] >= 0) {
                int bkt = meta[i] >> 13, r = meta[i] & 8191;
                staging[basepos[bkt] + r] = sv[i];
            }
        }
    }
}

// fill pass 2: one WG per bucket. Phase A: per-node counts (+rank in LDS) and
// per-(node,src) dedup via LDS hash. Then in-block scans -> row_off + norm.
// Phase B: scatter csr (L2-hot re-read, contiguous single-WG-owned writes).
__global__ __launch_bounds__(256) void fill2_kernel(
        const int* __restrict__ bucket_fill, const unsigned int* __restrict__ staging,
        int* __restrict__ csr_src, int* __restrict__ row_off,
        float* __restrict__ norm, int n_nodes) {
    __shared__ int cnt[512];
    __shared__ int off[513];
    __shared__ int bscan[256];
    __shared__ int pscan[256];
    __shared__ int dcount[512];
    __shared__ unsigned short rank16[CAP];   // 32 KB
    __shared__ unsigned int ht[HSLOTS];      // 64 KB
    __shared__ int s_base, s_total;
    int t = threadIdx.x;
    int b = blockIdx.x;
    int node0 = b << BSHIFT;
    int nn = min(512, n_nodes - node0);
    int v = (t < NB) ? bucket_fill[t] : 0;
    bscan[t] = v;
    for (int i = t; i < 512; i += 256) { cnt[i] = 0; dcount[i] = 0; }
    {
        uint4* h4 = (uint4*)ht;
        uint4 ff = make_uint4(0xFFFFFFFFu, 0xFFFFFFFFu, 0xFFFFFFFFu, 0xFFFFFFFFu);
        for (int i = t; i < HSLOTS / 4; i += 256) h4[i] = ff;
    }
    __syncthreads();
    for (int o = 1; o < 256; o <<= 1) {
        int xx = (t >= o) ? bscan[t - o] : 0;
        __syncthreads();
        bscan[t] += xx;
        __syncthreads();
    }
    if (t == b) { s_total = v; s_base = bscan[b] - v; }
    __syncthreads();
    int start = b << 14;
    int total = s_total;
    for (int li = t; li < total; li += 256) {
        unsigned int w = staging[start + li];
        int s = (int)(w & 0x1FFFFu);
        int dl = (int)(w >> 17);
        int r = atomicAdd(&cnt[dl], 1);
        rank16[li] = (unsigned short)r;
        if (s != node0 + dl) {
            unsigned int slot = ((w * 2654435761u) >> 12) & (HSLOTS - 1);
            while (true) {
                unsigned int prev = atomicCAS(&ht[slot], 0xFFFFFFFFu, w);
                if (prev == 0xFFFFFFFFu) { atomicAdd(&dcount[dl], 1); break; }
                if (prev == w) break;
                slot = (slot + 1) & (HSLOTS - 1);
            }
        }
    }
    __syncthreads();
    int c0 = cnt[2 * t], c1 = cnt[2 * t + 1];
    pscan[t] = c0 + c1;
    __syncthreads();
    for (int o = 1; o < 256; o <<= 1) {
        int xx = (t >= o) ? pscan[t - o] : 0;
        __syncthreads();
        pscan[t] += xx;
        __syncthreads();
    }
    int pe = pscan[t] - (c0 + c1);
    off[2 * t]     = s_base + pe;
    off[2 * t + 1] = s_base + pe + c0;
    if (t == 255) off[512] = s_base + pscan[255];
    __syncthreads();
    for (int i = t; i < nn; i += 256) {
        row_off[node0 + i] = off[i];
        norm[node0 + i] = 1.0f / (1.0f + (float)dcount[i]);
    }
    if (t == 0 && node0 + 512 >= n_nodes) row_off[n_nodes] = off[nn];
    for (int li = t; li < total; li += 256) {
        unsigned int w = staging[start + li];
        int s = (int)(w & 0x1FFFFu);
        int dl = (int)(w >> 17);
        csr_src[off[dl] + (int)rank16[li]] = s;
    }
}

// 8-wide-unrolled CSR gather-sum over the bf16 lin1 table (lane = channel).
__device__ __forceinline__ float gather_row_sum(const unsigned short* __restrict__ lin,
                                                const int* __restrict__ csr_src,
                                                int e0, int e1, int c) {
    float acc = 0.0f;
    int e = e0;
    for (; e + 8 <= e1; e += 8) {
        int s0 = csr_src[e + 0], s1 = csr_src[e + 1];
        int s2 = csr_src[e + 2], s3 = csr_src[e + 3];
        int s4 = csr_src[e + 4], s5 = csr_src[e + 5];
        int s6 = csr_src[e + 6], s7 = csr_src[e + 7];
        float v0 = bf2f(lin[s0 * 64 + c]), v1 = bf2f(lin[s1 * 64 + c]);
        float v2 = bf2f(lin[s2 * 64 + c]), v3 = bf2f(lin[s3 * 64 + c]);
        float v4 = bf2f(lin[s4 * 64 + c]), v5 = bf2f(lin[s5 * 64 + c]);
        float v6 = bf2f(lin[s6 * 64 + c]), v7 = bf2f(lin[s7 * 64 + c]);
        acc += ((v0 + v1) + (v2 + v3)) + ((v4 + v5) + (v6 + v7));
    }
    if (e + 4 <= e1) {
        int s0 = csr_src[e + 0], s1 = csr_src[e + 1];
        int s2 = csr_src[e + 2], s3 = csr_src[e + 3];
        float v0 = bf2f(lin[s0 * 64 + c]), v1 = bf2f(lin[s1 * 64 + c]);
        float v2 = bf2f(lin[s2 * 64 + c]), v3 = bf2f(lin[s3 * 64 + c]);
        acc += (v0 + v1) + (v2 + v3);
        e += 4;
    }
    for (; e < e1; e++) acc += bf2f(lin[csr_src[e] * 64 + c]);
    return acc;
}

// One wave per node: CSR gather-sum + PAN combine + relu (layer 1) fused with
// the rank-4 layer-2 projection: u[node][j] = h1[node] @ w44[:,j] + bias4[j].
__global__ void agg_h_kernel(const unsigned short* __restrict__ lin,
                             const int* __restrict__ row_off,
                             const int* __restrict__ csr_src, const float* __restrict__ norm,
                             const float* __restrict__ wpan, const float* __restrict__ w44,
                             const float* __restrict__ bias4, float* __restrict__ u,
                             int n_nodes) {
    int t = threadIdx.x;
    int node = blockIdx.x * 4 + (t >> 6);
    int c = t & 63;
    if (node >= n_nodes) return;
    int e0 = row_off[node], e1 = row_off[node + 1];
    float acc = gather_row_sum(lin, csr_src, e0, e1, c);
    float w0 = wpan[0];
    float w01 = wpan[0] * wpan[1];
    float v = norm[node] * (w0 * bf2f(lin[node * 64 + c]) + w01 * acc);
    v = fmaxf(v, 0.0f);                      // h1[node, c]
    float4 wv = *(const float4*)(w44 + c * 4);
    float a0 = v * wv.x, a1 = v * wv.y, a2 = v * wv.z, a3 = v * wv.w;
    for (int off = 32; off; off >>= 1) {
        a0 += __shfl_xor(a0, off);
        a1 += __shfl_xor(a1, off);
        a2 += __shfl_xor(a2, off);
        a3 += __shfl_xor(a3, off);
    }
    if (c == 0) {
        float4 bb = *(const float4*)bias4;
        *(float4*)(u + node * 4) =
            make_float4(a0 + bb.x, a1 + bb.y, a2 + bb.z, a3 + bb.w);
    }
}

// Layer-2 aggregate on the rank-4 table: pq[n,j] = norm*(w0*u[n,j] + w01*sum u[src,j]).
__global__ void agg_pq4_kernel(const float* __restrict__ u, const int* __restrict__ row_off,
                               const int* __restrict__ csr_src, const float* __restrict__ norm,
                               const float* __restrict__ wpan, float* __restrict__ pq,
                               int n_nodes) {
    int t = threadIdx.x;
    int node = blockIdx.x * 64 + (t >> 2);
    int j = t & 3;
    if (node >= n_nodes) return;
    int e0 = row_off[node], e1 = row_off[node + 1];
    float acc = 0.0f;
    int e = e0;
    for (; e + 4 <= e1; e += 4) {
        int s0 = csr_src[e + 0], s1 = csr_src[e + 1];
        int s2 = csr_src[e + 2], s3 = csr_src[e + 3];
        float v0 = u[s0 * 4 + j], v1 = u[s1 * 4 + j];
        float v2 = u[s2 * 4 + j], v3 = u[s3 * 4 + j];
        acc += (v0 + v1) + (v2 + v3);
    }
    for (; e < e1; e++) acc += u[csr_src[e] * 4 + j];
    float w0 = wpan[0];
    float w01 = wpan[0] * wpan[1];
    pq[node * 4 + j] = norm[node] * (w0 * u[node * 4 + j] + w01 * acc);
}

__global__ void edge_out_kernel(const int* __restrict__ src, const int* __restrict__ dst,
                                const float* __restrict__ pq, const float* __restrict__ bc,
                                float* __restrict__ out, int n_edges) {
    int e = blockIdx.x * blockDim.x + threadIdx.x;
    if (e >= n_edges) return;
    int r = src[e], c = dst[e];
    float2 p = *(const float2*)(pq + r * 4);
    float2 q = *(const float2*)(pq + c * 4 + 2);
    float2 o = make_float2(p.x + q.x + bc[0], p.y + q.y + bc[1]);
    *(float2*)(out + e * 2) = o;
}

extern "C" void kernel_launch(void* const* d_in, const int* in_sizes, int n_in,
                              void* d_out, int out_size, void* d_ws, size_t ws_size,
                              hipStream_t stream) {
    const float* x      = (const float*)d_in[0];
    const int*   eidx   = (const int*)d_in[1];
    const float* w1_lin = (const float*)d_in[2];
    const float* b1_lin = (const float*)d_in[3];
    const float* w1_pan = (const float*)d_in[4];
    const float* w2_lin = (const float*)d_in[5];
    const float* b2_lin = (const float*)d_in[6];
    const float* w2_pan = (const float*)d_in[7];
    const float* wc     = (const float*)d_in[8];
    const float* bc     = (const float*)d_in[9];
    float* out = (float*)d_out;

    const int* src = eidx;           // edge_index[0]
    const int* dst = eidx + NEDGES;  // edge_index[1]

    // ---- workspace carve-up (all 256B-aligned) ----
    char* ws = (char*)d_ws;
    size_t off = 0;
    auto carve = [&](size_t bytes) {
        char* p = ws + off;
        off = (off + bytes + 255) & ~(size_t)255;
        return p;
    };
    int*   bucket_fill = (int*)carve((size_t)NB * 4);
    int*   row_off  = (int*)carve((size_t)(NNODES + 1) * 4);
    unsigned int* staging = (unsigned int*)carve((size_t)NB * CAP * 4);  // 12.8 MB
    int*   csr_src  = (int*)carve((size_t)NEDGES * 4);
    float* nrm      = (float*)carve((size_t)NNODES * 4);
    unsigned short* bufA = (unsigned short*)carve((size_t)NNODES * HIDC * 2); // lin1 bf16
    float* u        = (float*)carve((size_t)NNODES * 4 * 4);     // rank-4 table
    float* pq       = (float*)carve((size_t)NNODES * 4 * 4);
    float* w44      = (float*)carve((size_t)64 * 4 * 4);
    float* bias4    = (float*)carve((size_t)4 * 4);
    (void)ws_size; (void)in_sizes; (void)n_in; (void)out_size;

    hipMemsetAsync(bucket_fill, 0, (size_t)NB * 4, stream);

    // fat kernel: layer-1 GEMM (bf16 out, + rank-4 weights) || edge binning
    const int nblk_fill = (NEDGES + TILE - 1) / TILE;  // 196
    lin_fill1_kernel<<<NBLK_LIN + nblk_fill, 256, 0, stream>>>(
        x, w1_lin, b1_lin, bufA, w2_lin, b2_lin, wc, w44, bias4,
        src, dst, bucket_fill, staging);

    // CSR build pass 2: row_off + dedup + norm + csr scatter
    fill2_kernel<<<NB, 256, 0, stream>>>(bucket_fill, staging, csr_src, row_off, nrm, NNODES);

    // layer 1 aggregate+relu fused with rank-4 projection -> u
    agg_h_kernel<<<(NNODES + 3) / 4, 256, 0, stream>>>(bufA, row_off, csr_src, nrm, w1_pan,
                                                       w44, bias4, u, NNODES);

    // layer 2 aggregate on the rank-4 table
    agg_pq4_kernel<<<(NNODES + 63) / 64, 256, 0, stream>>>(u, row_off, csr_src, nrm, w2_pan,
                                                           pq, NNODES);

    // edge head: out[e] = p[src[e]] + q[dst[e]] + bc
    edge_out_kernel<<<NEDGES / 256, 256, 0, stream>>>(src, dst, pq, bc, out, NEDGES);
}